// Round 7
// baseline (36580.038 us; speedup 1.0000x reference)
//
#include <hip/hip_runtime.h>
#include <hip/hip_bf16.h>

// TTS: embed -> BiLSTM encoder -> K/V proj -> 1000-step autoregressive decode.
// ALL-FP32 datapath (inputs/outputs/weights) — no bf16 staging, max accuracy
// margin. Decode: h(256/b)-recurrence, fused W2m=W2@Wmel, Wqh=Wq@Wmel;
// attended via per-head Wo partials + gate-side reduce. Persistent kernels.
// Barrier: distributed per-block flags (own 128B line, monotonic counter);
// arrive = 1 release-store, wait = wave-0 gather-poll + acquire fence
// (__builtin_amdgcn_fence — __hip_atomic_fence doesn't exist in this ROCm).

typedef unsigned short u16;
typedef unsigned int   u32;
#define DI __device__ __forceinline__

// ---- ws layout (bytes), total 2080KB ----
// flag slots: 48 slots x 32 flags x 128B.
//   slot g (0..7): barA decode group g (32 flags); 8+g: barB (16 flags);
//   16+k (k=0..31): encoder group k (8 flags).
static constexpr size_t WS_BAR   = 0;              // int[49152] 192KB
static constexpr size_t WS_HBUF  = 192*1024;       // fp32 [16][256] 16KB
static constexpr size_t WS_PROBS = 208*1024;       // fp32 [16][8][128] 64KB
static constexpr size_t WS_BIAS  = 272*1024;       // fp32 bqp[512]|bg0[1024]|bgp[1024]
static constexpr size_t WS_ATTB  = 288*1024;       // fp32 [16][8][512] 256KB
static constexpr size_t WS_W2M   = 544*1024;       // fp32 [1024][256] 1MB
static constexpr size_t WS_WQH   = 1568*1024;      // fp32 [512][256]  512KB -> 2080KB

// ---- d_out scratch (float indices; d_out = 8,210,048 floats) ----
// timeline: k_xw writes xw -> k_enc reads xw, writes enc -> k_proj reads enc,
// writes K/V -> k_decode reads K/V (prelude only), writes outputs.
// enc ∩ K/V = ∅, enc ∩ xw = ∅ (concurrently alive); xw ∩ K/V ok (xw dead).
// K/V for group g sits in group g's OWN mel rows (batch 2g, rows 0..511),
// first overwritten at step t=1 — after that group's barA(1)/barB(1).
static constexpr size_t OF_ENC_A = 262144;         // fp32 [8][128][512] b=0..7
static constexpr size_t OF_ENC_B = 1286144;        // fp32 [8][128][512] b=8..15
static constexpr size_t OF_XWF   = 4015744;        // fp32 [2048][1024]
static constexpr size_t OF_XWB   = 6112896;        // fp32 [2048][1024] -> 8210048
// K/V slot (group g, batch sub-index s): outf + g*1024000 + s*131072
//   K: [head][t][d] 65536 fl, then V: [head][d][t] 65536 fl.

DI float dot8f(float4 wa, float4 wb, float4 a, float4 b){
  return wa.x*a.x + wa.y*a.y + wa.z*a.z + wa.w*a.w
       + wb.x*b.x + wb.y*b.y + wb.z*b.z + wb.w*b.w;
}
DI float sigm(float x){ return 1.f/(1.f + __expf(-x)); }

// ---- distributed flag barrier ----
DI void bar_arrive(int* flags, int myidx, int t){
  __syncthreads();
  if (threadIdx.x == 0)
    __hip_atomic_store(flags + myidx*32, t, __ATOMIC_RELEASE, __HIP_MEMORY_SCOPE_AGENT);
}
DI void bar_wait(int* flags, int n, int t){
  if (threadIdx.x < 64){
    const int idx = threadIdx.x & (n-1);
    int v = __hip_atomic_load(flags + idx*32, __ATOMIC_RELAXED, __HIP_MEMORY_SCOPE_AGENT);
    while (__any(v < t)){
      __builtin_amdgcn_s_sleep(1);
      if (v < t)
        v = __hip_atomic_load(flags + idx*32, __ATOMIC_RELAXED, __HIP_MEMORY_SCOPE_AGENT);
    }
  }
  __builtin_amdgcn_fence(__ATOMIC_ACQUIRE, "agent");
  __syncthreads();
}

__global__ __launch_bounds__(256) void k_init(int* bars, float* hbuf){
  const int i = blockIdx.x*256 + threadIdx.x;   // 32 blocks
  for (int k = i; k < 49152; k += 32*256) bars[k] = 0;
  if (i < 4096) hbuf[i] = 0.f;
}

// fused embed + x@Wih.T + biases -> xw fp32. 2048 blocks.
__global__ __launch_bounds__(256) void k_xw(
    const int* __restrict__ tok, const int* __restrict__ spk,
    const float* __restrict__ et, const float* __restrict__ es,
    const float* __restrict__ WihF, const float* __restrict__ bihF, const float* __restrict__ bhhF,
    const float* __restrict__ WihB, const float* __restrict__ bihB, const float* __restrict__ bhhB,
    float* __restrict__ xwf, float* __restrict__ xwb){
  const int tid = threadIdx.x, bi = blockIdx.x;
  const int dir = bi & 1, jc = (bi >> 1) & 3, btg = bi >> 3;
  const int j = jc*256 + tid;
  const float* W = (dir ? WihB : WihF) + j*256;
  const float bias = (dir ? bihB : bihF)[j] + (dir ? bhhB : bhhF)[j];
  float* xw = dir ? xwb : xwf;

  __shared__ __align__(16) float lx[8][256];
  #pragma unroll
  for (int r = 0; r < 8; ++r){
    const int bt = btg*8 + r;
    lx[r][tid] = et[tok[bt]*256 + tid] + es[spk[bt>>7]*256 + tid];
  }
  __syncthreads();

  float acc[8];
  #pragma unroll
  for (int k2 = 0; k2 < 8; ++k2) acc[k2] = bias;
  for (int h = 0; h < 256; h += 8){
    float4 w0 = *(const float4*)(W + h);
    float4 w1 = *(const float4*)(W + h + 4);
    #pragma unroll
    for (int k2 = 0; k2 < 8; ++k2)
      acc[k2] += dot8f(w0, w1, *(const float4*)(&lx[k2][h]), *(const float4*)(&lx[k2][h+4]));
  }
  #pragma unroll
  for (int k2 = 0; k2 < 8; ++k2) xw[(btg*8 + k2)*1024 + j] = acc[k2];
}

// W2m = W2@Wmel fp32 [1024,256]; Wqh = Wq@Wmel fp32 [512,256]. 384 blocks.
__global__ __launch_bounds__(256) void k_fuse(
    const float* __restrict__ decW, const float* __restrict__ Wmel, const float* __restrict__ Wq,
    float* __restrict__ W2m, float* __restrict__ Wqh){
  const int tid = threadIdx.x, blk = blockIdx.x;
  float acc[4] = {0.f,0.f,0.f,0.f};
  const int h = tid;
  if (blk < 256){
    const int g0 = blk*4;
    for (int m = 0; m < 512; ++m){
      float wm = Wmel[m*256 + h];
      #pragma unroll
      for (int i2 = 0; i2 < 4; ++i2) acc[i2] += decW[(g0+i2)*1024 + 512 + m] * wm;
    }
    #pragma unroll
    for (int i2 = 0; i2 < 4; ++i2) W2m[(g0+i2)*256 + h] = acc[i2];
  } else {
    const int j0 = (blk - 256)*4;
    for (int e = 0; e < 512; ++e){
      float wm = Wmel[e*256 + h];
      #pragma unroll
      for (int i2 = 0; i2 < 4; ++i2) acc[i2] += Wq[(j0+i2)*512 + e] * wm;
    }
    #pragma unroll
    for (int i2 = 0; i2 < 4; ++i2) Wqh[(j0+i2)*256 + h] = acc[i2];
  }
}

__global__ __launch_bounds__(256) void k_bias(
    const float* __restrict__ Wq, const float* __restrict__ bq, const float* __restrict__ bmel,
    const float* __restrict__ decW, const float* __restrict__ bo,
    const float* __restrict__ bih, const float* __restrict__ bhh, float* __restrict__ biasws){
  const int o = blockIdx.x*256 + threadIdx.x;   // 6 blocks -> 1536
  if (o < 512){
    float s = bq[o];
    for (int e = 0; e < 512; ++e) s += Wq[o*512 + e] * bmel[e];
    biasws[o] = s;                               // bq' = Wq@bmel + bq
  } else {
    const int gr = o - 512;
    float s1 = bih[gr] + bhh[gr];
    for (int jj = 0; jj < 512; ++jj) s1 += decW[gr*1024 + jj] * bo[jj];
    biasws[512 + gr] = s1;                       // bg0 = W1@bo + bih + bhh
    float s2 = s1;
    for (int m = 0; m < 512; ++m) s2 += decW[gr*1024 + 512 + m] * bmel[m];
    biasws[1536 + gr] = s2;                      // bg' = bg0 + W2@bmel
  }
}

// persistent BiLSTM encoder: 32 groups (dir,b) x 8 WGs x 128 thr. All fp32.
__global__ __launch_bounds__(128) void k_enc(
    const float* __restrict__ xwf, const float* __restrict__ xwb,
    const float* __restrict__ WhhF, const float* __restrict__ WhhB,
    float* __restrict__ encA, float* __restrict__ encB, int* bars){
  const int tid = threadIdx.x;
  const int xcd = blockIdx.x & 7, sl = blockIdx.x >> 3;
  const int grp = xcd*4 + (sl >> 3);
  const int w = sl & 7;
  const int dir = grp & 1, b = grp >> 1;
  int* bar = bars + (16 + grp)*1024;
  const float* Whh = dir ? WhhB : WhhF;
  const float* xw = dir ? xwb : xwf;
  float* encb = (b < 8 ? encA : encB) + (size_t)(b & 7)*65536;
  const int q = tid >> 5, ii = tid & 31;
  const int j = q*256 + w*32 + ii;
  const float* wr = Whh + j*256;

  __shared__ float l_g[4][32];
  __shared__ float l_c[32];
  if (tid < 32) l_c[tid] = 0.f;
  __syncthreads();

  for (int it = 0; it < 128; ++it){
    const int ts = dir ? (127 - it) : it;
    float acc = xw[(b*128 + ts)*1024 + j];
    if (it > 0){
      const int tp = dir ? (ts + 1) : (ts - 1);
      const float* hp = encb + tp*512 + dir*256;
      #pragma unroll 4
      for (int k = 0; k < 256; k += 8)
        acc += dot8f(*(const float4*)(wr + k), *(const float4*)(wr + k + 4),
                     *(const float4*)(hp + k), *(const float4*)(hp + k + 4));
    }
    l_g[q][ii] = acc;
    __syncthreads();
    if (tid < 32){
      float ig = l_g[0][tid], fg = l_g[1][tid], gg = l_g[2][tid], og = l_g[3][tid];
      float c = sigm(fg)*l_c[tid] + sigm(ig)*tanhf(gg);
      l_c[tid] = c;
      encb[ts*512 + dir*256 + w*32 + tid] = sigm(og)*tanhf(c);
    }
    bar_arrive(bar, w, it+1);
    bar_wait(bar, 8, it+1);
  }
}

// K,V projections fp32 -> per-group slot in d_out. 1024 blocks.
__global__ __launch_bounds__(256) void k_proj(
    const float* __restrict__ encA, const float* __restrict__ encB,
    const float* __restrict__ Wk, const float* __restrict__ bk,
    const float* __restrict__ Wv, const float* __restrict__ bv,
    float* outf){
  const int tid = threadIdx.x, x = blockIdx.x;
  const int role = x & 1, dc = (x >> 1) & 1, btg = x >> 2;
  const int row = dc*256 + tid;
  const float* W = (role ? Wv : Wk) + row*512;
  const float bias = (role ? bv : bk)[row];
  const int b = (btg*8) >> 7;                       // all 8 rows same batch
  const float* eb = (b < 8 ? encA : encB) + (size_t)(b & 7)*65536;
  float acc[8];
  #pragma unroll
  for (int k2 = 0; k2 < 8; ++k2) acc[k2] = bias;
  for (int e = 0; e < 512; e += 8){
    float4 wa = *(const float4*)(W + e);
    float4 wb = *(const float4*)(W + e + 4);
    #pragma unroll
    for (int k2 = 0; k2 < 8; ++k2){
      const float* ep = eb + ((btg*8 + k2) & 127)*512 + e;
      acc[k2] += dot8f(wa, wb, *(const float4*)(ep), *(const float4*)(ep + 4));
    }
  }
  const int head = row >> 6, dd = row & 63;
  float* kv = outf + (size_t)(b >> 1)*1024000 + (size_t)(b & 1)*131072;
  #pragma unroll
  for (int k2 = 0; k2 < 8; ++k2){
    const int ts = (btg*8 + k2) & 127;
    if (role == 0) kv[head*8192 + ts*64 + dd] = acc[k2];
    else           kv[65536 + head*8192 + dd*128 + ts] = acc[k2];
  }
}

// persistent decoder: 8 groups (b-pair) x 32 WGs x 256 thr; 2 flag-barriers/step.
__global__ __launch_bounds__(256) void k_decode(
    const float* __restrict__ Wmel, const float* __restrict__ bmel,
    const float* __restrict__ Wstop, const float* __restrict__ bstop,
    const float* __restrict__ bq, const float* __restrict__ Wo,
    const float* __restrict__ decW,
    const float* __restrict__ W2m, const float* __restrict__ Wqh,
    const float* __restrict__ biasws,
    float* __restrict__ hbuf, float* __restrict__ attb, float* __restrict__ probs,
    int* bars, float* out){   // out NOT restrict: K/V slots alias mel region
  const int tid = threadIdx.x;
  const int g = blockIdx.x & 7, slot = blockIdx.x >> 3;
  const int b0 = g*2;
  int* barA = bars + g*1024;
  int* barB = bars + (8+g)*1024;
  const float* bqp = biasws;
  const float* bg0 = biasws + 512;
  const float* bgp = biasws + 1536;
  float* out_mel  = out;
  float* out_stop = out + 8192000;
  float* out_attn = out + 8208000;

  // fp32 K stride 68, V stride 132: 8-lane bank tiling, conflict-free b128.
  __shared__ __align__(16) float lK[128*68];
  __shared__ __align__(16) float lV[64*132];
  __shared__ __align__(16) float l_t4[4][64];
  __shared__ __align__(16) float l_q[64];
  __shared__ __align__(16) float l_p[128];
  __shared__ __align__(16) float l_ctx[64];
  __shared__ float l_r[4];
  __shared__ __align__(16) float l_att[1024];
  __shared__ float l_w2[256];
  __shared__ float l_gc[256];
  __shared__ float l_gate[128];

  if (slot < 16){
    // ---------------- attention slot (b,head) ----------------
    const int b = b0 + (slot >> 3), head = slot & 7;
    const int d = tid & 63, kq = tid >> 6;
    {  // prelude: K,V -> LDS from this group's own slot (before any mel write)
      const float* kv = out + (size_t)g*1024000 + (size_t)(slot >> 3)*131072;
      const float* gK = kv + head*8192;
      const float* gV = kv + 65536 + head*8192;
      for (int i = tid; i < 2048; i += 256){
        const int r = i >> 4, c = i & 15;
        *(float4*)(lK + r*68 + c*4) = *(const float4*)(gK + r*64 + c*4);
      }
      for (int i = tid; i < 2048; i += 256){
        const int r = i >> 5, c = i & 31;
        *(float4*)(lV + r*132 + c*4) = *(const float4*)(gV + r*128 + c*4);
      }
      __syncthreads();
    }
    const float* wqr = Wqh + (head*64 + d)*256 + kq*64;
    const float* hpq = hbuf + b*256 + kq*64;
    for (int t = 0; t < 1000; ++t){
      float qp = 0.f;
      if (t > 0){
        #pragma unroll
        for (int k = 0; k < 64; k += 8)
          qp += dot8f(*(const float4*)(wqr + k), *(const float4*)(wqr + k + 4),
                      *(const float4*)(hpq + k), *(const float4*)(hpq + k + 4));
      }
      l_t4[kq][d] = qp;
      __syncthreads();
      if (tid < 64){
        float qq = l_t4[0][tid] + l_t4[1][tid] + l_t4[2][tid] + l_t4[3][tid];
        qq += (t == 0) ? bq[head*64 + tid] : bqp[head*64 + tid];
        l_q[tid] = qq;
      }
      __syncthreads();
      float s = 0.f;
      if (tid < 128){
        const float* kr = lK + tid*68;
        #pragma unroll
        for (int k = 0; k < 64; k += 8)
          s += dot8f(*(const float4*)(kr + k), *(const float4*)(kr + k + 4),
                     *(const float4*)(l_q + k), *(const float4*)(l_q + k + 4));
        s *= 0.125f;
        float m = s;
        #pragma unroll
        for (int off = 32; off; off >>= 1) m = fmaxf(m, __shfl_xor(m, off));
        if ((tid & 63) == 0) l_r[tid >> 6] = m;
      }
      __syncthreads();
      float p = 0.f;
      if (tid < 128){
        float M = fmaxf(l_r[0], l_r[1]);
        p = __expf(s - M);
        float ss = p;
        #pragma unroll
        for (int off = 32; off; off >>= 1) ss += __shfl_xor(ss, off);
        if ((tid & 63) == 0) l_r[2 + (tid >> 6)] = ss;
      }
      __syncthreads();
      if (tid < 128){
        p /= (l_r[2] + l_r[3]);
        l_p[tid] = p;
        if (t == 999) probs[(b*8 + head)*128 + tid] = p;
      }
      __syncthreads();
      {
        const float* vr = lV + d*132 + kq*32;
        float cp = 0.f;
        #pragma unroll
        for (int k = 0; k < 32; k += 8)
          cp += dot8f(*(const float4*)(vr + k), *(const float4*)(vr + k + 4),
                      *(const float4*)(l_p + kq*32 + k), *(const float4*)(l_p + kq*32 + k + 4));
        l_t4[kq][d] = cp;
      }
      __syncthreads();
      if (tid < 64)
        l_ctx[tid] = l_t4[0][tid] + l_t4[1][tid] + l_t4[2][tid] + l_t4[3][tid];
      __syncthreads();
      // attended partials (sans bo): attb[b][head][j] = Wo[j, head*64:+64] @ ctx
      for (int jj = tid; jj < 512; jj += 256){
        const float* wo = Wo + jj*512 + head*64;
        float a = 0.f;
        #pragma unroll
        for (int k = 0; k < 64; k += 8)
          a += dot8f(*(const float4*)(wo + k), *(const float4*)(wo + k + 4),
                     *(const float4*)(l_ctx + k), *(const float4*)(l_ctx + k + 4));
        attb[((size_t)(b*8 + head))*512 + jj] = a;
      }
      bar_arrive(barA, slot, t+1);   // publish partials; don't wait on A
      bar_wait(barB, 16, t+1);       // wait for h_t
    }
    if (tid < 16){
      const int tt = (slot & 7)*16 + tid;
      float ssum = 0.f;
      #pragma unroll
      for (int h8 = 0; h8 < 8; ++h8) ssum += probs[(b*8 + h8)*128 + tt];
      out_attn[b*128 + tt] = ssum * 0.125f;
    }
  } else {
    // ---------------- gate slot ----------------
    const int w = slot - 16;
    const int bmb = b0 + (w >> 3);
    const int r0 = (w & 7)*64;
    const int rl = tid & 63, bl = (tid >> 6) & 1, half = tid >> 7;
    const int j = (rl >> 4)*256 + w*16 + (rl & 15);
    for (int t = 0; t <= 1000; ++t){
      if (t >= 1){
        const int r = r0 + (tid & 63), kq = tid >> 6;
        const float* wr = Wmel + r*256 + kq*64;
        const float* hp = hbuf + bmb*256 + kq*64;
        float mp = 0.f;
        #pragma unroll
        for (int k = 0; k < 64; k += 8)
          mp += dot8f(*(const float4*)(wr + k), *(const float4*)(wr + k + 4),
                      *(const float4*)(hp + k), *(const float4*)(hp + k + 4));
        l_t4[kq][tid & 63] = mp;
        __syncthreads();
        if (tid < 64){
          float v = l_t4[0][tid] + l_t4[1][tid] + l_t4[2][tid] + l_t4[3][tid] + bmel[r0 + tid];
          out_mel[((size_t)bmb*1000 + (t-1))*512 + r0 + tid] = v;
        }
        if ((w & 7) == 0 && tid < 64){
          const float* hp2 = hbuf + bmb*256;
          float sp = 0.f;
          #pragma unroll
          for (int k2 = 0; k2 < 4; ++k2) sp += Wstop[tid*4 + k2] * hp2[tid*4 + k2];
          #pragma unroll
          for (int off = 32; off; off >>= 1) sp += __shfl_xor(sp, off);
          if (tid == 0) out_stop[bmb*1000 + (t-1)] = sp + bstop[0];
        }
      }
      if (t == 1000) break;
      {  // phase A: W2m @ h_{t-1} partials
        const float* wr = W2m + j*256 + half*128;
        const float* hp = hbuf + (b0 + bl)*256 + half*128;
        float acc = 0.f;
        #pragma unroll 4
        for (int k = 0; k < 128; k += 8)
          acc += dot8f(*(const float4*)(wr + k), *(const float4*)(wr + k + 4),
                       *(const float4*)(hp + k), *(const float4*)(hp + k + 4));
        l_w2[tid] = acc;
      }
      bar_arrive(barA, slot, t+1);
      bar_wait(barA, 32, t+1);       // wait for attended partials
      // reduce partials over heads -> l_att[2][512]   (bo folded into bg0/bgp)
      for (int i = tid; i < 1024; i += 256){
        const int bl3 = i >> 9, jj = i & 511;
        const float* ap = attb + ((size_t)(b0 + bl3)*8)*512 + jj;
        float s2 = 0.f;
        #pragma unroll
        for (int h8 = 0; h8 < 8; ++h8) s2 += ap[h8*512];
        l_att[i] = s2;
      }
      __syncthreads();
      {  // phase B: gates = W1@attended + W2m@h + bias -> h_t
        const float* wr = decW + j*1024 + half*256;
        const float* ap2 = l_att + bl*512 + half*256;
        float acc = 0.f;
        #pragma unroll 4
        for (int k = 0; k < 256; k += 8)
          acc += dot8f(*(const float4*)(wr + k), *(const float4*)(wr + k + 4),
                       *(const float4*)(ap2 + k), *(const float4*)(ap2 + k + 4));
        l_gc[tid] = acc;
      }
      __syncthreads();
      if (tid < 128){
        const int rl2 = tid & 63, bl2 = tid >> 6;
        const int j2 = (rl2 >> 4)*256 + w*16 + (rl2 & 15);
        float gate = l_gc[bl2*64 + rl2] + l_gc[128 + bl2*64 + rl2]
                   + l_w2[bl2*64 + rl2] + l_w2[128 + bl2*64 + rl2]
                   + ((t == 0) ? bg0[j2] : bgp[j2]);
        l_gate[bl2*64 + rl2] = gate;
      }
      __syncthreads();
      if (tid < 32){
        const int il = tid & 15, bl2 = tid >> 4;
        float ig = l_gate[bl2*64 + il];
        float gg = l_gate[bl2*64 + 32 + il];
        float og = l_gate[bl2*64 + 48 + il];
        float c = sigm(ig)*tanhf(gg);              // decoder c_prev == 0 every step
        hbuf[(b0 + bl2)*256 + w*16 + il] = sigm(og)*tanhf(c);
      }
      bar_arrive(barB, w, t+1);
      bar_wait(barB, 16, t+1);
    }
  }
}

extern "C" void kernel_launch(void* const* d_in, const int* in_sizes, int n_in,
                              void* d_out, int out_size, void* d_ws, size_t ws_size,
                              hipStream_t stream){
  const int*   tok = (const int*)d_in[0];
  const int*   spk = (const int*)d_in[1];
  const float* emb_text = (const float*)d_in[2];
  const float* emb_spk  = (const float*)d_in[3];
  const float* WihF = (const float*)d_in[4];
  const float* WhhF = (const float*)d_in[5];
  const float* bihF = (const float*)d_in[6];
  const float* bhhF = (const float*)d_in[7];
  const float* WihB = (const float*)d_in[8];
  const float* WhhB = (const float*)d_in[9];
  const float* bihB = (const float*)d_in[10];
  const float* bhhB = (const float*)d_in[11];
  const float* Wq = (const float*)d_in[12];
  const float* bq = (const float*)d_in[13];
  const float* Wk = (const float*)d_in[14];
  const float* bk = (const float*)d_in[15];
  const float* Wv = (const float*)d_in[16];
  const float* bv = (const float*)d_in[17];
  const float* Wo = (const float*)d_in[18];
  const float* bo = (const float*)d_in[19];
  const float* decW = (const float*)d_in[20];
  /* d_in[21] dec_Whh dead (state re-zeroed every step) */
  const float* bih = (const float*)d_in[22];
  const float* bhh = (const float*)d_in[23];
  const float* Wmel = (const float*)d_in[24];
  const float* bmel = (const float*)d_in[25];
  const float* Wstop = (const float*)d_in[26];
  const float* bstop = (const float*)d_in[27];

  char* ws = (char*)d_ws;
  int*   bars   = (int*)(ws + WS_BAR);
  float* hbuf   = (float*)(ws + WS_HBUF);
  float* probs  = (float*)(ws + WS_PROBS);
  float* biasws = (float*)(ws + WS_BIAS);
  float* attb   = (float*)(ws + WS_ATTB);
  float* W2m    = (float*)(ws + WS_W2M);
  float* Wqh    = (float*)(ws + WS_WQH);

  float* outf = (float*)d_out;
  float* encA = outf + OF_ENC_A;
  float* encB = outf + OF_ENC_B;
  float* xwf  = outf + OF_XWF;
  float* xwb  = outf + OF_XWB;

  k_init <<<32,   256, 0, stream>>>(bars, hbuf);
  k_xw   <<<2048, 256, 0, stream>>>(tok, spk, emb_text, emb_spk,
                                    WihF, bihF, bhhF, WihB, bihB, bhhB, xwf, xwb);
  k_enc  <<<256,  128, 0, stream>>>(xwf, xwb, WhhF, WhhB, encA, encB, bars);
  k_fuse <<<384,  256, 0, stream>>>(decW, Wmel, Wq, W2m, Wqh);
  k_bias <<<6,    256, 0, stream>>>(Wq, bq, bmel, decW, bo, bih, bhh, biasws);
  k_proj <<<1024, 256, 0, stream>>>(encA, encB, Wk, bk, Wv, bv, outf);
  k_decode<<<256, 256, 0, stream>>>(Wmel, bmel, Wstop, bstop, bq, Wo, decW,
                                    W2m, Wqh, biasws,
                                    hbuf, attb, probs, bars, outf);
}

// Round 8
// 31162.106 us; speedup vs baseline: 1.1739x; 1.1739x over previous
//
#include <hip/hip_runtime.h>
#include <hip/hip_bf16.h>

// TTS: embed -> BiLSTM encoder -> K/V proj -> 1000-step autoregressive decode.
// Mixed precision: gate-path weights (W1=decW[:,:512], W2m, Wo) staged bf16 so
// the per-XCD decode working set (~3MB) stays L2-resident; Wmel/Wqh/K/V fp32
// (accuracy-critical: direct mel path + attention logits). fp32 accumulate.
// Decode: h(256/b)-recurrence; attended via per-head Wo partials + gate-side
// reduce. Persistent kernels. Barrier: distributed per-block flags (own 128B
// line, monotonic counter); arrive = 1 release-store, wait = gather-poll +
// agent acquire fence (__builtin_amdgcn_fence).

typedef unsigned short u16;
typedef unsigned int   u32;
#define DI __device__ __forceinline__

// ---- ws layout (bytes), total 3104KB ----
static constexpr size_t WS_BAR   = 0;              // int[49152] 192KB (flag lines)
static constexpr size_t WS_HBUF  = 192*1024;       // fp32 [16][256] 16KB
static constexpr size_t WS_PROBS = 208*1024;       // fp32 [16][8][128] 64KB
static constexpr size_t WS_BIAS  = 272*1024;       // fp32 bqp[512]|bg0[1024]|bgp[1024]
static constexpr size_t WS_ATTB  = 288*1024;       // fp32 [16][8][512] 256KB
static constexpr size_t WS_W2M   = 544*1024;       // bf16 [1024][256] 512KB
static constexpr size_t WS_WQH   = 1056*1024;      // fp32 [512][256]  512KB
static constexpr size_t WS_WOB   = 1568*1024;      // bf16 [512][512]  512KB
static constexpr size_t WS_W1B   = 2080*1024;      // bf16 [1024][512] 1MB -> 3104KB

// ---- d_out scratch (float indices; d_out = 8,210,048 floats) ----
// enc ∩ K/V = ∅, enc ∩ xw = ∅; xw ∩ K/V ok (xw dead at k_proj).
// K/V for group g sits in group g's OWN mel rows, overwritten only after
// that group's barA(1)/barB(1) chain.
static constexpr size_t OF_ENC_A = 262144;         // fp32 [8][128][512] b=0..7
static constexpr size_t OF_ENC_B = 1286144;        // fp32 [8][128][512] b=8..15
static constexpr size_t OF_XWF   = 4015744;        // fp32 [2048][1024]
static constexpr size_t OF_XWB   = 6112896;        // fp32 [2048][1024] -> 8210048
// K/V slot (group g, batch sub s): outf + g*1024000 + s*131072 (K then V^T)

DI float bf2f(u16 u){ union{u32 i; float f;} v; v.i = ((u32)u)<<16; return v.f; }
DI u16 f2bf(float f){ union{float f; u32 i;} v; v.f = f;
  u32 r = v.i + 0x7fffu + ((v.i>>16)&1u); return (u16)(r>>16); }
DI float2 bf2x(u32 u){ union{u32 i; float f;} a,b; a.i = u<<16; b.i = u & 0xffff0000u;
  float2 r; r.x = a.f; r.y = b.f; return r; }
DI float dot8(uint4 wv, float4 a, float4 b){   // bf16 weights x fp32 acts
  float2 w0 = bf2x(wv.x), w1 = bf2x(wv.y), w2 = bf2x(wv.z), w3 = bf2x(wv.w);
  return w0.x*a.x + w0.y*a.y + w1.x*a.z + w1.y*a.w
       + w2.x*b.x + w2.y*b.y + w3.x*b.z + w3.y*b.w;
}
DI float dot8f(float4 wa, float4 wb, float4 a, float4 b){
  return wa.x*a.x + wa.y*a.y + wa.z*a.z + wa.w*a.w
       + wb.x*b.x + wb.y*b.y + wb.z*b.z + wb.w*b.w;
}
DI float sigm(float x){ return 1.f/(1.f + __expf(-x)); }

// ---- distributed flag barrier ----
DI void bar_arrive(int* flags, int myidx, int t){
  __syncthreads();
  if (threadIdx.x == 0)
    __hip_atomic_store(flags + myidx*32, t, __ATOMIC_RELEASE, __HIP_MEMORY_SCOPE_AGENT);
}
DI void bar_wait(int* flags, int n, int t){
  if (threadIdx.x < 64){
    const int idx = threadIdx.x & (n-1);
    int v = __hip_atomic_load(flags + idx*32, __ATOMIC_RELAXED, __HIP_MEMORY_SCOPE_AGENT);
    while (__any(v < t)){
      __builtin_amdgcn_s_sleep(1);
      if (v < t)
        v = __hip_atomic_load(flags + idx*32, __ATOMIC_RELAXED, __HIP_MEMORY_SCOPE_AGENT);
    }
  }
  __builtin_amdgcn_fence(__ATOMIC_ACQUIRE, "agent");
  __syncthreads();
}

__global__ __launch_bounds__(256) void k_init(int* bars, float* hbuf){
  const int i = blockIdx.x*256 + threadIdx.x;   // 32 blocks
  for (int k = i; k < 49152; k += 32*256) bars[k] = 0;
  if (i < 4096) hbuf[i] = 0.f;
}

// fused embed + x@Wih.T + biases -> xw fp32. 2048 blocks.
__global__ __launch_bounds__(256) void k_xw(
    const int* __restrict__ tok, const int* __restrict__ spk,
    const float* __restrict__ et, const float* __restrict__ es,
    const float* __restrict__ WihF, const float* __restrict__ bihF, const float* __restrict__ bhhF,
    const float* __restrict__ WihB, const float* __restrict__ bihB, const float* __restrict__ bhhB,
    float* __restrict__ xwf, float* __restrict__ xwb){
  const int tid = threadIdx.x, bi = blockIdx.x;
  const int dir = bi & 1, jc = (bi >> 1) & 3, btg = bi >> 3;
  const int j = jc*256 + tid;
  const float* W = (dir ? WihB : WihF) + j*256;
  const float bias = (dir ? bihB : bihF)[j] + (dir ? bhhB : bhhF)[j];
  float* xw = dir ? xwb : xwf;

  __shared__ __align__(16) float lx[8][256];
  #pragma unroll
  for (int r = 0; r < 8; ++r){
    const int bt = btg*8 + r;
    lx[r][tid] = et[tok[bt]*256 + tid] + es[spk[bt>>7]*256 + tid];
  }
  __syncthreads();

  float acc[8];
  #pragma unroll
  for (int k2 = 0; k2 < 8; ++k2) acc[k2] = bias;
  for (int h = 0; h < 256; h += 8){
    float4 w0 = *(const float4*)(W + h);
    float4 w1 = *(const float4*)(W + h + 4);
    #pragma unroll
    for (int k2 = 0; k2 < 8; ++k2)
      acc[k2] += dot8f(w0, w1, *(const float4*)(&lx[k2][h]), *(const float4*)(&lx[k2][h+4]));
  }
  #pragma unroll
  for (int k2 = 0; k2 < 8; ++k2) xw[(btg*8 + k2)*1024 + j] = acc[k2];
}

// bf16 staging: Wob [512][512], W1b = decW[:, :512] [1024][512]. 3072 blocks.
__global__ __launch_bounds__(256) void k_cvt(
    const float* __restrict__ Wo, const float* __restrict__ decW,
    u16* __restrict__ Wob, u16* __restrict__ W1b){
  const int idx = blockIdx.x*256 + threadIdx.x;
  if (idx < 262144){
    Wob[idx] = f2bf(Wo[idx]);
  } else {
    const int i = idx - 262144;
    W1b[i] = f2bf(decW[(i >> 9)*1024 + (i & 511)]);
  }
}

// W2m = W2@Wmel -> bf16 [1024,256]; Wqh = Wq@Wmel -> fp32 [512,256]. 384 blocks.
__global__ __launch_bounds__(256) void k_fuse(
    const float* __restrict__ decW, const float* __restrict__ Wmel, const float* __restrict__ Wq,
    u16* __restrict__ W2m, float* __restrict__ Wqh){
  const int tid = threadIdx.x, blk = blockIdx.x;
  float acc[4] = {0.f,0.f,0.f,0.f};
  const int h = tid;
  if (blk < 256){
    const int g0 = blk*4;
    for (int m = 0; m < 512; ++m){
      float wm = Wmel[m*256 + h];
      #pragma unroll
      for (int i2 = 0; i2 < 4; ++i2) acc[i2] += decW[(g0+i2)*1024 + 512 + m] * wm;
    }
    #pragma unroll
    for (int i2 = 0; i2 < 4; ++i2) W2m[(g0+i2)*256 + h] = f2bf(acc[i2]);
  } else {
    const int j0 = (blk - 256)*4;
    for (int e = 0; e < 512; ++e){
      float wm = Wmel[e*256 + h];
      #pragma unroll
      for (int i2 = 0; i2 < 4; ++i2) acc[i2] += Wq[(j0+i2)*512 + e] * wm;
    }
    #pragma unroll
    for (int i2 = 0; i2 < 4; ++i2) Wqh[(j0+i2)*256 + h] = acc[i2];
  }
}

__global__ __launch_bounds__(256) void k_bias(
    const float* __restrict__ Wq, const float* __restrict__ bq, const float* __restrict__ bmel,
    const float* __restrict__ decW, const float* __restrict__ bo,
    const float* __restrict__ bih, const float* __restrict__ bhh, float* __restrict__ biasws){
  const int o = blockIdx.x*256 + threadIdx.x;   // 6 blocks -> 1536
  if (o < 512){
    float s = bq[o];
    for (int e = 0; e < 512; ++e) s += Wq[o*512 + e] * bmel[e];
    biasws[o] = s;                               // bq' = Wq@bmel + bq
  } else {
    const int gr = o - 512;
    float s1 = bih[gr] + bhh[gr];
    for (int jj = 0; jj < 512; ++jj) s1 += decW[gr*1024 + jj] * bo[jj];
    biasws[512 + gr] = s1;                       // bg0 = W1@bo + bih + bhh
    float s2 = s1;
    for (int m = 0; m < 512; ++m) s2 += decW[gr*1024 + 512 + m] * bmel[m];
    biasws[1536 + gr] = s2;                      // bg' = bg0 + W2@bmel
  }
}

// persistent BiLSTM encoder: 32 groups (dir,b) x 8 WGs x 128 thr. All fp32.
__global__ __launch_bounds__(128) void k_enc(
    const float* __restrict__ xwf, const float* __restrict__ xwb,
    const float* __restrict__ WhhF, const float* __restrict__ WhhB,
    float* __restrict__ encA, float* __restrict__ encB, int* bars){
  const int tid = threadIdx.x;
  const int xcd = blockIdx.x & 7, sl = blockIdx.x >> 3;
  const int grp = xcd*4 + (sl >> 3);
  const int w = sl & 7;
  const int dir = grp & 1, b = grp >> 1;
  int* bar = bars + (16 + grp)*1024;
  const float* Whh = dir ? WhhB : WhhF;
  const float* xw = dir ? xwb : xwf;
  float* encb = (b < 8 ? encA : encB) + (size_t)(b & 7)*65536;
  const int q = tid >> 5, ii = tid & 31;
  const int j = q*256 + w*32 + ii;
  const float* wr = Whh + j*256;

  __shared__ float l_g[4][32];
  __shared__ float l_c[32];
  if (tid < 32) l_c[tid] = 0.f;
  __syncthreads();

  for (int it = 0; it < 128; ++it){
    const int ts = dir ? (127 - it) : it;
    float acc = xw[(b*128 + ts)*1024 + j];
    if (it > 0){
      const int tp = dir ? (ts + 1) : (ts - 1);
      const float* hp = encb + tp*512 + dir*256;
      #pragma unroll 4
      for (int k = 0; k < 256; k += 8)
        acc += dot8f(*(const float4*)(wr + k), *(const float4*)(wr + k + 4),
                     *(const float4*)(hp + k), *(const float4*)(hp + k + 4));
    }
    l_g[q][ii] = acc;
    __syncthreads();
    if (tid < 32){
      float ig = l_g[0][tid], fg = l_g[1][tid], gg = l_g[2][tid], og = l_g[3][tid];
      float c = sigm(fg)*l_c[tid] + sigm(ig)*tanhf(gg);
      l_c[tid] = c;
      encb[ts*512 + dir*256 + w*32 + tid] = sigm(og)*tanhf(c);
    }
    bar_arrive(bar, w, it+1);
    bar_wait(bar, 8, it+1);
  }
}

// K,V projections fp32 -> per-group slot in d_out. 1024 blocks.
__global__ __launch_bounds__(256) void k_proj(
    const float* __restrict__ encA, const float* __restrict__ encB,
    const float* __restrict__ Wk, const float* __restrict__ bk,
    const float* __restrict__ Wv, const float* __restrict__ bv,
    float* outf){
  const int tid = threadIdx.x, x = blockIdx.x;
  const int role = x & 1, dc = (x >> 1) & 1, btg = x >> 2;
  const int row = dc*256 + tid;
  const float* W = (role ? Wv : Wk) + row*512;
  const float bias = (role ? bv : bk)[row];
  const int b = (btg*8) >> 7;
  const float* eb = (b < 8 ? encA : encB) + (size_t)(b & 7)*65536;
  float acc[8];
  #pragma unroll
  for (int k2 = 0; k2 < 8; ++k2) acc[k2] = bias;
  for (int e = 0; e < 512; e += 8){
    float4 wa = *(const float4*)(W + e);
    float4 wb = *(const float4*)(W + e + 4);
    #pragma unroll
    for (int k2 = 0; k2 < 8; ++k2){
      const float* ep = eb + ((btg*8 + k2) & 127)*512 + e;
      acc[k2] += dot8f(wa, wb, *(const float4*)(ep), *(const float4*)(ep + 4));
    }
  }
  const int head = row >> 6, dd = row & 63;
  float* kv = outf + (size_t)(b >> 1)*1024000 + (size_t)(b & 1)*131072;
  #pragma unroll
  for (int k2 = 0; k2 < 8; ++k2){
    const int ts = (btg*8 + k2) & 127;
    if (role == 0) kv[head*8192 + ts*64 + dd] = acc[k2];
    else           kv[65536 + head*8192 + dd*128 + ts] = acc[k2];
  }
}

// persistent decoder: 8 groups (b-pair) x 32 WGs x 256 thr; 2 flag-barriers/step.
__global__ __launch_bounds__(256) void k_decode(
    const float* __restrict__ Wmel, const float* __restrict__ bmel,
    const float* __restrict__ Wstop, const float* __restrict__ bstop,
    const float* __restrict__ bq,
    const u16* __restrict__ Wob, const u16* __restrict__ W1b,
    const u16* __restrict__ W2m, const float* __restrict__ Wqh,
    const float* __restrict__ biasws,
    float* __restrict__ hbuf, float* __restrict__ attb, float* __restrict__ probs,
    int* bars, float* out){   // out NOT restrict: K/V slots alias mel region
  const int tid = threadIdx.x;
  const int g = blockIdx.x & 7, slot = blockIdx.x >> 3;
  const int b0 = g*2;
  int* barA = bars + g*1024;
  int* barB = bars + (8+g)*1024;
  const float* bqp = biasws;
  const float* bg0 = biasws + 512;
  const float* bgp = biasws + 1536;
  float* out_mel  = out;
  float* out_stop = out + 8192000;
  float* out_attn = out + 8208000;

  // fp32 K stride 68, V stride 132: conflict-free b128 row reads.
  __shared__ __align__(16) float lK[128*68];
  __shared__ __align__(16) float lV[64*132];
  __shared__ __align__(16) float l_t4[4][64];
  __shared__ __align__(16) float l_q[64];
  __shared__ __align__(16) float l_p[128];
  __shared__ __align__(16) float l_ctx[64];
  __shared__ float l_r[4];
  __shared__ __align__(16) float l_att[1024];
  __shared__ float l_w2[256];
  __shared__ float l_gc[256];
  __shared__ float l_gate[128];

  if (slot < 16){
    // ---------------- attention slot (b,head) ----------------
    const int b = b0 + (slot >> 3), head = slot & 7;
    const int d = tid & 63, kq = tid >> 6;
    {  // prelude: K,V -> LDS from this group's own slot (before any mel write)
      const float* kv = out + (size_t)g*1024000 + (size_t)(slot >> 3)*131072;
      const float* gK = kv + head*8192;
      const float* gV = kv + 65536 + head*8192;
      for (int i = tid; i < 2048; i += 256){
        const int r = i >> 4, c = i & 15;
        *(float4*)(lK + r*68 + c*4) = *(const float4*)(gK + r*64 + c*4);
      }
      for (int i = tid; i < 2048; i += 256){
        const int r = i >> 5, c = i & 31;
        *(float4*)(lV + r*132 + c*4) = *(const float4*)(gV + r*128 + c*4);
      }
      __syncthreads();
    }
    const float* wqr = Wqh + (head*64 + d)*256 + kq*64;
    const float* hpq = hbuf + b*256 + kq*64;
    for (int t = 0; t < 1000; ++t){
      float qp = 0.f;
      if (t > 0){
        #pragma unroll
        for (int k = 0; k < 64; k += 8)
          qp += dot8f(*(const float4*)(wqr + k), *(const float4*)(wqr + k + 4),
                      *(const float4*)(hpq + k), *(const float4*)(hpq + k + 4));
      }
      l_t4[kq][d] = qp;
      __syncthreads();
      if (tid < 64){
        float qq = l_t4[0][tid] + l_t4[1][tid] + l_t4[2][tid] + l_t4[3][tid];
        qq += (t == 0) ? bq[head*64 + tid] : bqp[head*64 + tid];
        l_q[tid] = qq;
      }
      __syncthreads();
      float s = 0.f;
      if (tid < 128){
        const float* kr = lK + tid*68;
        #pragma unroll
        for (int k = 0; k < 64; k += 8)
          s += dot8f(*(const float4*)(kr + k), *(const float4*)(kr + k + 4),
                     *(const float4*)(l_q + k), *(const float4*)(l_q + k + 4));
        s *= 0.125f;
        float m = s;
        #pragma unroll
        for (int off = 32; off; off >>= 1) m = fmaxf(m, __shfl_xor(m, off));
        if ((tid & 63) == 0) l_r[tid >> 6] = m;
      }
      __syncthreads();
      float p = 0.f;
      if (tid < 128){
        float M = fmaxf(l_r[0], l_r[1]);
        p = __expf(s - M);
        float ss = p;
        #pragma unroll
        for (int off = 32; off; off >>= 1) ss += __shfl_xor(ss, off);
        if ((tid & 63) == 0) l_r[2 + (tid >> 6)] = ss;
      }
      __syncthreads();
      if (tid < 128){
        p /= (l_r[2] + l_r[3]);
        l_p[tid] = p;
        if (t == 999) probs[(b*8 + head)*128 + tid] = p;
      }
      __syncthreads();
      {
        const float* vr = lV + d*132 + kq*32;
        float cp = 0.f;
        #pragma unroll
        for (int k = 0; k < 32; k += 8)
          cp += dot8f(*(const float4*)(vr + k), *(const float4*)(vr + k + 4),
                      *(const float4*)(l_p + kq*32 + k), *(const float4*)(l_p + kq*32 + k + 4));
        l_t4[kq][d] = cp;
      }
      __syncthreads();
      if (tid < 64)
        l_ctx[tid] = l_t4[0][tid] + l_t4[1][tid] + l_t4[2][tid] + l_t4[3][tid];
      __syncthreads();
      // attended partials (sans bo): attb[b][head][j] = Wo[j, head*64:+64] @ ctx
      for (int jj = tid; jj < 512; jj += 256){
        const u16* wo = Wob + jj*512 + head*64;
        float a = 0.f;
        #pragma unroll
        for (int k = 0; k < 64; k += 8)
          a += dot8(*(const uint4*)(wo + k), *(const float4*)(l_ctx + k), *(const float4*)(l_ctx + k + 4));
        attb[((size_t)(b*8 + head))*512 + jj] = a;
      }
      bar_arrive(barA, slot, t+1);   // publish partials; don't wait on A
      bar_wait(barB, 16, t+1);       // wait for h_t
    }
    if (tid < 16){
      const int tt = (slot & 7)*16 + tid;
      float ssum = 0.f;
      #pragma unroll
      for (int h8 = 0; h8 < 8; ++h8) ssum += probs[(b*8 + h8)*128 + tt];
      out_attn[b*128 + tt] = ssum * 0.125f;
    }
  } else {
    // ---------------- gate slot ----------------
    const int w = slot - 16;
    const int bmb = b0 + (w >> 3);
    const int r0 = (w & 7)*64;
    const int rl = tid & 63, bl = (tid >> 6) & 1, half = tid >> 7;
    const int j = (rl >> 4)*256 + w*16 + (rl & 15);
    for (int t = 0; t <= 1000; ++t){
      if (t >= 1){
        const int r = r0 + (tid & 63), kq = tid >> 6;
        const float* wr = Wmel + r*256 + kq*64;       // fp32: direct mel path
        const float* hp = hbuf + bmb*256 + kq*64;
        float mp = 0.f;
        #pragma unroll
        for (int k = 0; k < 64; k += 8)
          mp += dot8f(*(const float4*)(wr + k), *(const float4*)(wr + k + 4),
                      *(const float4*)(hp + k), *(const float4*)(hp + k + 4));
        l_t4[kq][tid & 63] = mp;
        __syncthreads();
        if (tid < 64){
          float v = l_t4[0][tid] + l_t4[1][tid] + l_t4[2][tid] + l_t4[3][tid] + bmel[r0 + tid];
          out_mel[((size_t)bmb*1000 + (t-1))*512 + r0 + tid] = v;
        }
        if ((w & 7) == 0 && tid < 64){
          const float* hp2 = hbuf + bmb*256;
          float sp = 0.f;
          #pragma unroll
          for (int k2 = 0; k2 < 4; ++k2) sp += Wstop[tid*4 + k2] * hp2[tid*4 + k2];
          #pragma unroll
          for (int off = 32; off; off >>= 1) sp += __shfl_xor(sp, off);
          if (tid == 0) out_stop[bmb*1000 + (t-1)] = sp + bstop[0];
        }
      }
      if (t == 1000) break;
      {  // phase A: W2m @ h_{t-1} partials (bf16 weights)
        const u16* wr = W2m + j*256 + half*128;
        const float* hp = hbuf + (b0 + bl)*256 + half*128;
        float acc = 0.f;
        #pragma unroll 4
        for (int k = 0; k < 128; k += 8)
          acc += dot8(*(const uint4*)(wr + k), *(const float4*)(hp + k), *(const float4*)(hp + k + 4));
        l_w2[tid] = acc;
      }
      bar_arrive(barA, slot, t+1);
      bar_wait(barA, 32, t+1);       // wait for attended partials
      // reduce partials over heads -> l_att[2][512]   (bo folded into bg0/bgp)
      for (int i = tid; i < 1024; i += 256){
        const int bl3 = i >> 9, jj = i & 511;
        const float* ap = attb + ((size_t)(b0 + bl3)*8)*512 + jj;
        float s2 = 0.f;
        #pragma unroll
        for (int h8 = 0; h8 < 8; ++h8) s2 += ap[h8*512];
        l_att[i] = s2;
      }
      __syncthreads();
      {  // phase B: gates = W1@attended + W2m@h + bias -> h_t (bf16 W1)
        const u16* wr = W1b + j*512 + half*256;
        const float* ap2 = l_att + bl*512 + half*256;
        float acc = 0.f;
        #pragma unroll 4
        for (int k = 0; k < 256; k += 8)
          acc += dot8(*(const uint4*)(wr + k), *(const float4*)(ap2 + k), *(const float4*)(ap2 + k + 4));
        l_gc[tid] = acc;
      }
      __syncthreads();
      if (tid < 128){
        const int rl2 = tid & 63, bl2 = tid >> 6;
        const int j2 = (rl2 >> 4)*256 + w*16 + (rl2 & 15);
        float gate = l_gc[bl2*64 + rl2] + l_gc[128 + bl2*64 + rl2]
                   + l_w2[bl2*64 + rl2] + l_w2[128 + bl2*64 + rl2]
                   + ((t == 0) ? bg0[j2] : bgp[j2]);
        l_gate[bl2*64 + rl2] = gate;
      }
      __syncthreads();
      if (tid < 32){
        const int il = tid & 15, bl2 = tid >> 4;
        float ig = l_gate[bl2*64 + il];
        float gg = l_gate[bl2*64 + 32 + il];
        float og = l_gate[bl2*64 + 48 + il];
        float c = sigm(ig)*tanhf(gg);              // decoder c_prev == 0 every step
        hbuf[(b0 + bl2)*256 + w*16 + il] = sigm(og)*tanhf(c);
      }
      bar_arrive(barB, w, t+1);
      bar_wait(barB, 16, t+1);
    }
  }
}

extern "C" void kernel_launch(void* const* d_in, const int* in_sizes, int n_in,
                              void* d_out, int out_size, void* d_ws, size_t ws_size,
                              hipStream_t stream){
  const int*   tok = (const int*)d_in[0];
  const int*   spk = (const int*)d_in[1];
  const float* emb_text = (const float*)d_in[2];
  const float* emb_spk  = (const float*)d_in[3];
  const float* WihF = (const float*)d_in[4];
  const float* WhhF = (const float*)d_in[5];
  const float* bihF = (const float*)d_in[6];
  const float* bhhF = (const float*)d_in[7];
  const float* WihB = (const float*)d_in[8];
  const float* WhhB = (const float*)d_in[9];
  const float* bihB = (const float*)d_in[10];
  const float* bhhB = (const float*)d_in[11];
  const float* Wq = (const float*)d_in[12];
  const float* bq = (const float*)d_in[13];
  const float* Wk = (const float*)d_in[14];
  const float* bk = (const float*)d_in[15];
  const float* Wv = (const float*)d_in[16];
  const float* bv = (const float*)d_in[17];
  const float* Wo = (const float*)d_in[18];
  const float* bo = (const float*)d_in[19];
  const float* decW = (const float*)d_in[20];
  /* d_in[21] dec_Whh dead (state re-zeroed every step) */
  const float* bih = (const float*)d_in[22];
  const float* bhh = (const float*)d_in[23];
  const float* Wmel = (const float*)d_in[24];
  const float* bmel = (const float*)d_in[25];
  const float* Wstop = (const float*)d_in[26];
  const float* bstop = (const float*)d_in[27];

  char* ws = (char*)d_ws;
  int*   bars   = (int*)(ws + WS_BAR);
  float* hbuf   = (float*)(ws + WS_HBUF);
  float* probs  = (float*)(ws + WS_PROBS);
  float* biasws = (float*)(ws + WS_BIAS);
  float* attb   = (float*)(ws + WS_ATTB);
  u16*   W2m    = (u16*)(ws + WS_W2M);
  float* Wqh    = (float*)(ws + WS_WQH);
  u16*   Wob    = (u16*)(ws + WS_WOB);
  u16*   W1b    = (u16*)(ws + WS_W1B);

  float* outf = (float*)d_out;
  float* encA = outf + OF_ENC_A;
  float* encB = outf + OF_ENC_B;
  float* xwf  = outf + OF_XWF;
  float* xwb  = outf + OF_XWB;

  k_init <<<32,   256, 0, stream>>>(bars, hbuf);
  k_xw   <<<2048, 256, 0, stream>>>(tok, spk, emb_text, emb_spk,
                                    WihF, bihF, bhhF, WihB, bihB, bhhB, xwf, xwb);
  k_enc  <<<256,  128, 0, stream>>>(xwf, xwb, WhhF, WhhB, encA, encB, bars);
  k_cvt  <<<3072, 256, 0, stream>>>(Wo, decW, Wob, W1b);
  k_fuse <<<384,  256, 0, stream>>>(decW, Wmel, Wq, W2m, Wqh);
  k_bias <<<6,    256, 0, stream>>>(Wq, bq, bmel, decW, bo, bih, bhh, biasws);
  k_proj <<<1024, 256, 0, stream>>>(encA, encB, Wk, bk, Wv, bv, outf);
  k_decode<<<256, 256, 0, stream>>>(Wmel, bmel, Wstop, bstop, bq,
                                    Wob, W1b, W2m, Wqh, biasws,
                                    hbuf, attb, probs, bars, outf);
}

// Round 9
// 15749.120 us; speedup vs baseline: 2.3227x; 1.9787x over previous
//
#include <hip/hip_runtime.h>
#include <hip/hip_bf16.h>

// TTS: embed -> BiLSTM encoder -> K/V proj -> 1000-step autoregressive decode.
// Mixed precision: gate-path weights (W1, W2m, Wo) bf16 (L2-resident ~3MB/XCD);
// Wmel/Wqh/K/V fp32. fp32 accumulate everywhere.
// Sync: FENCE-FREE flag barriers. All cross-block data moves via agent-scope
// RELAXED atomics (cache-bypassing, always fresh) staged into LDS; flags are
// relaxed stores after __syncthreads (whose s_barrier drains vmcnt(0)) +
// s_waitcnt(0). No acquire fence -> per-XCD L2 (weights) never invalidated.

typedef unsigned short u16;
typedef unsigned int   u32;
#define DI __device__ __forceinline__

// ---- ws layout (bytes), total 3104KB ----
static constexpr size_t WS_BAR   = 0;              // int[49152] 192KB (flag lines)
static constexpr size_t WS_HBUF  = 192*1024;       // fp32 [16][256] 16KB
static constexpr size_t WS_PROBS = 208*1024;       // fp32 [16][8][128] 64KB
static constexpr size_t WS_BIAS  = 272*1024;       // fp32 bqp[512]|bg0[1024]|bgp[1024]
static constexpr size_t WS_ATTB  = 288*1024;       // fp32 [16][8][512] 256KB
static constexpr size_t WS_W2M   = 544*1024;       // bf16 [1024][256] 512KB
static constexpr size_t WS_WQH   = 1056*1024;      // fp32 [512][256]  512KB
static constexpr size_t WS_WOB   = 1568*1024;      // bf16 [512][512]  512KB
static constexpr size_t WS_W1B   = 2080*1024;      // bf16 [1024][512] 1MB -> 3104KB

// ---- d_out scratch (float indices; d_out = 8,210,048 floats) ----
static constexpr size_t OF_ENC_A = 262144;         // fp32 [8][128][512] b=0..7
static constexpr size_t OF_ENC_B = 1286144;        // fp32 [8][128][512] b=8..15
static constexpr size_t OF_XWF   = 4015744;        // fp32 [2048][1024]
static constexpr size_t OF_XWB   = 6112896;        // fp32 [2048][1024] -> 8210048
// K/V slot (group g, batch sub s): outf + g*1024000 + s*131072 (K then V^T)

DI float bf2f(u16 u){ union{u32 i; float f;} v; v.i = ((u32)u)<<16; return v.f; }
DI u16 f2bf(float f){ union{float f; u32 i;} v; v.f = f;
  u32 r = v.i + 0x7fffu + ((v.i>>16)&1u); return (u16)(r>>16); }
DI float2 bf2x(u32 u){ union{u32 i; float f;} a,b; a.i = u<<16; b.i = u & 0xffff0000u;
  float2 r; r.x = a.f; r.y = b.f; return r; }
DI float dot8(uint4 wv, float4 a, float4 b){   // bf16 weights x fp32 acts
  float2 w0 = bf2x(wv.x), w1 = bf2x(wv.y), w2 = bf2x(wv.z), w3 = bf2x(wv.w);
  return w0.x*a.x + w0.y*a.y + w1.x*a.z + w1.y*a.w
       + w2.x*b.x + w2.y*b.y + w3.x*b.z + w3.y*b.w;
}
DI float dot8f(float4 wa, float4 wb, float4 a, float4 b){
  return wa.x*a.x + wa.y*a.y + wa.z*a.z + wa.w*a.w
       + wb.x*b.x + wb.y*b.y + wb.z*b.z + wb.w*b.w;
}
DI float sigm(float x){ return 1.f/(1.f + __expf(-x)); }

// agent-scope relaxed atomics: cache-bypassing, no fence needed.
DI float afload(const float* p){
  return __hip_atomic_load(p, __ATOMIC_RELAXED, __HIP_MEMORY_SCOPE_AGENT);
}
DI void afstore(float* p, float v){
  __hip_atomic_store(p, v, __ATOMIC_RELAXED, __HIP_MEMORY_SCOPE_AGENT);
}

// ---- fence-free flag barrier ----
// arrive: __syncthreads (drains vmcnt(0) per wave before s_barrier) then one
// relaxed flag store. wait: gather-poll relaxed + compiler barrier ONLY — no
// acquire fence, so L2 (weights) is never invalidated. All data crossing the
// barrier travels via afload/afstore (coherence-point reads/writes).
DI void bar_arrive(int* flags, int myidx, int t){
  __syncthreads();
  if (threadIdx.x == 0){
    __builtin_amdgcn_s_waitcnt(0);
    __hip_atomic_store(flags + myidx*32, t, __ATOMIC_RELAXED, __HIP_MEMORY_SCOPE_AGENT);
  }
}
DI void bar_wait(int* flags, int n, int t){
  if (threadIdx.x < 64){
    const int idx = threadIdx.x & (n-1);
    int v = __hip_atomic_load(flags + idx*32, __ATOMIC_RELAXED, __HIP_MEMORY_SCOPE_AGENT);
    while (__any(v < t)){
      __builtin_amdgcn_s_sleep(1);
      if (v < t)
        v = __hip_atomic_load(flags + idx*32, __ATOMIC_RELAXED, __HIP_MEMORY_SCOPE_AGENT);
    }
  }
  __asm__ __volatile__("" ::: "memory");
  __syncthreads();
}

__global__ __launch_bounds__(256) void k_init(int* bars, float* hbuf){
  const int i = blockIdx.x*256 + threadIdx.x;   // 32 blocks
  for (int k = i; k < 49152; k += 32*256) bars[k] = 0;
  if (i < 4096) hbuf[i] = 0.f;
}

// fused embed + x@Wih.T + biases -> xw fp32. 2048 blocks.
__global__ __launch_bounds__(256) void k_xw(
    const int* __restrict__ tok, const int* __restrict__ spk,
    const float* __restrict__ et, const float* __restrict__ es,
    const float* __restrict__ WihF, const float* __restrict__ bihF, const float* __restrict__ bhhF,
    const float* __restrict__ WihB, const float* __restrict__ bihB, const float* __restrict__ bhhB,
    float* __restrict__ xwf, float* __restrict__ xwb){
  const int tid = threadIdx.x, bi = blockIdx.x;
  const int dir = bi & 1, jc = (bi >> 1) & 3, btg = bi >> 3;
  const int j = jc*256 + tid;
  const float* W = (dir ? WihB : WihF) + j*256;
  const float bias = (dir ? bihB : bihF)[j] + (dir ? bhhB : bhhF)[j];
  float* xw = dir ? xwb : xwf;

  __shared__ __align__(16) float lx[8][256];
  #pragma unroll
  for (int r = 0; r < 8; ++r){
    const int bt = btg*8 + r;
    lx[r][tid] = et[tok[bt]*256 + tid] + es[spk[bt>>7]*256 + tid];
  }
  __syncthreads();

  float acc[8];
  #pragma unroll
  for (int k2 = 0; k2 < 8; ++k2) acc[k2] = bias;
  for (int h = 0; h < 256; h += 8){
    float4 w0 = *(const float4*)(W + h);
    float4 w1 = *(const float4*)(W + h + 4);
    #pragma unroll
    for (int k2 = 0; k2 < 8; ++k2)
      acc[k2] += dot8f(w0, w1, *(const float4*)(&lx[k2][h]), *(const float4*)(&lx[k2][h+4]));
  }
  #pragma unroll
  for (int k2 = 0; k2 < 8; ++k2) xw[(btg*8 + k2)*1024 + j] = acc[k2];
}

// bf16 staging: Wob [512][512], W1b = decW[:, :512] [1024][512]. 3072 blocks.
__global__ __launch_bounds__(256) void k_cvt(
    const float* __restrict__ Wo, const float* __restrict__ decW,
    u16* __restrict__ Wob, u16* __restrict__ W1b){
  const int idx = blockIdx.x*256 + threadIdx.x;
  if (idx < 262144){
    Wob[idx] = f2bf(Wo[idx]);
  } else {
    const int i = idx - 262144;
    W1b[i] = f2bf(decW[(i >> 9)*1024 + (i & 511)]);
  }
}

// W2m = W2@Wmel -> bf16 [1024,256]; Wqh = Wq@Wmel -> fp32 [512,256]. 384 blocks.
__global__ __launch_bounds__(256) void k_fuse(
    const float* __restrict__ decW, const float* __restrict__ Wmel, const float* __restrict__ Wq,
    u16* __restrict__ W2m, float* __restrict__ Wqh){
  const int tid = threadIdx.x, blk = blockIdx.x;
  float acc[4] = {0.f,0.f,0.f,0.f};
  const int h = tid;
  if (blk < 256){
    const int g0 = blk*4;
    for (int m = 0; m < 512; ++m){
      float wm = Wmel[m*256 + h];
      #pragma unroll
      for (int i2 = 0; i2 < 4; ++i2) acc[i2] += decW[(g0+i2)*1024 + 512 + m] * wm;
    }
    #pragma unroll
    for (int i2 = 0; i2 < 4; ++i2) W2m[(g0+i2)*256 + h] = f2bf(acc[i2]);
  } else {
    const int j0 = (blk - 256)*4;
    for (int e = 0; e < 512; ++e){
      float wm = Wmel[e*256 + h];
      #pragma unroll
      for (int i2 = 0; i2 < 4; ++i2) acc[i2] += Wq[(j0+i2)*512 + e] * wm;
    }
    #pragma unroll
    for (int i2 = 0; i2 < 4; ++i2) Wqh[(j0+i2)*256 + h] = acc[i2];
  }
}

__global__ __launch_bounds__(256) void k_bias(
    const float* __restrict__ Wq, const float* __restrict__ bq, const float* __restrict__ bmel,
    const float* __restrict__ decW, const float* __restrict__ bo,
    const float* __restrict__ bih, const float* __restrict__ bhh, float* __restrict__ biasws){
  const int o = blockIdx.x*256 + threadIdx.x;   // 6 blocks -> 1536
  if (o < 512){
    float s = bq[o];
    for (int e = 0; e < 512; ++e) s += Wq[o*512 + e] * bmel[e];
    biasws[o] = s;                               // bq' = Wq@bmel + bq
  } else {
    const int gr = o - 512;
    float s1 = bih[gr] + bhh[gr];
    for (int jj = 0; jj < 512; ++jj) s1 += decW[gr*1024 + jj] * bo[jj];
    biasws[512 + gr] = s1;                       // bg0 = W1@bo + bih + bhh
    float s2 = s1;
    for (int m = 0; m < 512; ++m) s2 += decW[gr*1024 + 512 + m] * bmel[m];
    biasws[1536 + gr] = s2;                      // bg' = bg0 + W2@bmel
  }
}

// persistent BiLSTM encoder: 32 groups (dir,b) x 8 WGs x 128 thr. fp32.
// enc h exchanged via relaxed agent atomics staged into LDS; fence-free barrier.
__global__ __launch_bounds__(128) void k_enc(
    const float* __restrict__ xwf, const float* __restrict__ xwb,
    const float* __restrict__ WhhF, const float* __restrict__ WhhB,
    float* encA, float* encB, int* bars){
  const int tid = threadIdx.x;
  const int xcd = blockIdx.x & 7, sl = blockIdx.x >> 3;
  const int grp = xcd*4 + (sl >> 3);
  const int w = sl & 7;
  const int dir = grp & 1, b = grp >> 1;
  int* bar = bars + (16 + grp)*1024;
  const float* Whh = dir ? WhhB : WhhF;
  const float* xw = dir ? xwb : xwf;
  float* encb = (b < 8 ? encA : encB) + (size_t)(b & 7)*65536;
  const int q = tid >> 5, ii = tid & 31;
  const int j = q*256 + w*32 + ii;
  const float* wr = Whh + j*256;

  __shared__ __align__(16) float l_h[256];
  __shared__ float l_g[4][32];
  __shared__ float l_c[32];
  if (tid < 32) l_c[tid] = 0.f;
  __syncthreads();

  for (int it = 0; it < 128; ++it){
    const int ts = dir ? (127 - it) : it;
    float acc = xw[(b*128 + ts)*1024 + j];
    if (it > 0){
      const int tp = dir ? (ts + 1) : (ts - 1);
      const float* hp = encb + tp*512 + dir*256;
      for (int i = tid; i < 256; i += 128) l_h[i] = afload(hp + i);
      __syncthreads();
      #pragma unroll 4
      for (int k = 0; k < 256; k += 8)
        acc += dot8f(*(const float4*)(wr + k), *(const float4*)(wr + k + 4),
                     *(const float4*)(&l_h[k]), *(const float4*)(&l_h[k + 4]));
    }
    l_g[q][ii] = acc;
    __syncthreads();
    if (tid < 32){
      float ig = l_g[0][tid], fg = l_g[1][tid], gg = l_g[2][tid], og = l_g[3][tid];
      float c = sigm(fg)*l_c[tid] + sigm(ig)*tanhf(gg);
      l_c[tid] = c;
      afstore(encb + ts*512 + dir*256 + w*32 + tid, sigm(og)*tanhf(c));
    }
    bar_arrive(bar, w, it+1);
    bar_wait(bar, 8, it+1);
  }
}

// K,V projections fp32 -> per-group slot in d_out. 1024 blocks.
__global__ __launch_bounds__(256) void k_proj(
    const float* __restrict__ encA, const float* __restrict__ encB,
    const float* __restrict__ Wk, const float* __restrict__ bk,
    const float* __restrict__ Wv, const float* __restrict__ bv,
    float* outf){
  const int tid = threadIdx.x, x = blockIdx.x;
  const int role = x & 1, dc = (x >> 1) & 1, btg = x >> 2;
  const int row = dc*256 + tid;
  const float* W = (role ? Wv : Wk) + row*512;
  const float bias = (role ? bv : bk)[row];
  const int b = (btg*8) >> 7;
  const float* eb = (b < 8 ? encA : encB) + (size_t)(b & 7)*65536;
  float acc[8];
  #pragma unroll
  for (int k2 = 0; k2 < 8; ++k2) acc[k2] = bias;
  for (int e = 0; e < 512; e += 8){
    float4 wa = *(const float4*)(W + e);
    float4 wb = *(const float4*)(W + e + 4);
    #pragma unroll
    for (int k2 = 0; k2 < 8; ++k2){
      const float* ep = eb + ((btg*8 + k2) & 127)*512 + e;
      acc[k2] += dot8f(wa, wb, *(const float4*)(ep), *(const float4*)(ep + 4));
    }
  }
  const int head = row >> 6, dd = row & 63;
  float* kv = outf + (size_t)(b >> 1)*1024000 + (size_t)(b & 1)*131072;
  #pragma unroll
  for (int k2 = 0; k2 < 8; ++k2){
    const int ts = (btg*8 + k2) & 127;
    if (role == 0) kv[head*8192 + ts*64 + dd] = acc[k2];
    else           kv[65536 + head*8192 + dd*128 + ts] = acc[k2];
  }
}

// persistent decoder: 8 groups (b-pair) x 32 WGs x 256 thr; 2 fence-free
// flag-barriers/step; hbuf/attb/probs via relaxed agent atomics.
__global__ __launch_bounds__(256) void k_decode(
    const float* __restrict__ Wmel, const float* __restrict__ bmel,
    const float* __restrict__ Wstop, const float* __restrict__ bstop,
    const float* __restrict__ bq,
    const u16* __restrict__ Wob, const u16* __restrict__ W1b,
    const u16* __restrict__ W2m, const float* __restrict__ Wqh,
    const float* __restrict__ biasws,
    float* hbuf, float* attb, float* probs,
    int* bars, float* out){   // out NOT restrict: K/V slots alias mel region
  const int tid = threadIdx.x;
  const int g = blockIdx.x & 7, slot = blockIdx.x >> 3;
  const int b0 = g*2;
  int* barA = bars + g*1024;
  int* barB = bars + (8+g)*1024;
  const float* bqp = biasws;
  const float* bg0 = biasws + 512;
  const float* bgp = biasws + 1536;
  float* out_mel  = out;
  float* out_stop = out + 8192000;
  float* out_attn = out + 8208000;

  // fp32 K stride 68, V stride 132: conflict-free b128 row reads.
  __shared__ __align__(16) float lK[128*68];
  __shared__ __align__(16) float lV[64*132];
  __shared__ __align__(16) float l_t4[4][64];
  __shared__ __align__(16) float l_q[64];
  __shared__ __align__(16) float l_p[128];
  __shared__ __align__(16) float l_ctx[64];
  __shared__ float l_r[4];
  __shared__ __align__(16) float l_att[1024];
  __shared__ __align__(16) float l_h[512];
  __shared__ float l_w2[256];
  __shared__ float l_gc[256];
  __shared__ float l_gate[128];

  if (slot < 16){
    // ---------------- attention slot (b,head) ----------------
    const int b = b0 + (slot >> 3), head = slot & 7;
    const int d = tid & 63, kq = tid >> 6;
    {  // prelude: K,V -> LDS from this group's own slot (before any mel write)
      const float* kv = out + (size_t)g*1024000 + (size_t)(slot >> 3)*131072;
      const float* gK = kv + head*8192;
      const float* gV = kv + 65536 + head*8192;
      for (int i = tid; i < 2048; i += 256){
        const int r = i >> 4, c = i & 15;
        *(float4*)(lK + r*68 + c*4) = *(const float4*)(gK + r*64 + c*4);
      }
      for (int i = tid; i < 2048; i += 256){
        const int r = i >> 5, c = i & 31;
        *(float4*)(lV + r*132 + c*4) = *(const float4*)(gV + r*128 + c*4);
      }
      __syncthreads();
    }
    const float* wqr = Wqh + (head*64 + d)*256 + kq*64;
    for (int t = 0; t < 1000; ++t){
      float qp = 0.f;
      if (t > 0){
        l_h[tid] = afload(hbuf + b*256 + tid);   // stage h_{t-1}
        __syncthreads();
        const float* hpq = l_h + kq*64;
        #pragma unroll
        for (int k = 0; k < 64; k += 8)
          qp += dot8f(*(const float4*)(wqr + k), *(const float4*)(wqr + k + 4),
                      *(const float4*)(hpq + k), *(const float4*)(hpq + k + 4));
      }
      l_t4[kq][d] = qp;
      __syncthreads();
      if (tid < 64){
        float qq = l_t4[0][tid] + l_t4[1][tid] + l_t4[2][tid] + l_t4[3][tid];
        qq += (t == 0) ? bq[head*64 + tid] : bqp[head*64 + tid];
        l_q[tid] = qq;
      }
      __syncthreads();
      float s = 0.f;
      if (tid < 128){
        const float* kr = lK + tid*68;
        #pragma unroll
        for (int k = 0; k < 64; k += 8)
          s += dot8f(*(const float4*)(kr + k), *(const float4*)(kr + k + 4),
                     *(const float4*)(l_q + k), *(const float4*)(l_q + k + 4));
        s *= 0.125f;
        float m = s;
        #pragma unroll
        for (int off = 32; off; off >>= 1) m = fmaxf(m, __shfl_xor(m, off));
        if ((tid & 63) == 0) l_r[tid >> 6] = m;
      }
      __syncthreads();
      float p = 0.f;
      if (tid < 128){
        float M = fmaxf(l_r[0], l_r[1]);
        p = __expf(s - M);
        float ss = p;
        #pragma unroll
        for (int off = 32; off; off >>= 1) ss += __shfl_xor(ss, off);
        if ((tid & 63) == 0) l_r[2 + (tid >> 6)] = ss;
      }
      __syncthreads();
      if (tid < 128){
        p /= (l_r[2] + l_r[3]);
        l_p[tid] = p;
        if (t == 999) afstore(probs + (b*8 + head)*128 + tid, p);
      }
      __syncthreads();
      {
        const float* vr = lV + d*132 + kq*32;
        float cp = 0.f;
        #pragma unroll
        for (int k = 0; k < 32; k += 8)
          cp += dot8f(*(const float4*)(vr + k), *(const float4*)(vr + k + 4),
                      *(const float4*)(l_p + kq*32 + k), *(const float4*)(l_p + kq*32 + k + 4));
        l_t4[kq][d] = cp;
      }
      __syncthreads();
      if (tid < 64)
        l_ctx[tid] = l_t4[0][tid] + l_t4[1][tid] + l_t4[2][tid] + l_t4[3][tid];
      __syncthreads();
      // attended partials (sans bo): attb[b][head][j] = Wo[j, head*64:+64] @ ctx
      for (int jj = tid; jj < 512; jj += 256){
        const u16* wo = Wob + jj*512 + head*64;
        float a = 0.f;
        #pragma unroll
        for (int k = 0; k < 64; k += 8)
          a += dot8(*(const uint4*)(wo + k), *(const float4*)(l_ctx + k), *(const float4*)(l_ctx + k + 4));
        afstore(attb + ((size_t)(b*8 + head))*512 + jj, a);
      }
      bar_arrive(barA, slot, t+1);   // publish partials; don't wait on A
      bar_wait(barB, 16, t+1);       // wait for h_t
    }
    if (tid < 16){
      const int tt = (slot & 7)*16 + tid;
      float ssum = 0.f;
      #pragma unroll
      for (int h8 = 0; h8 < 8; ++h8) ssum += afload(probs + (b*8 + h8)*128 + tt);
      out_attn[b*128 + tt] = ssum * 0.125f;
    }
  } else {
    // ---------------- gate slot ----------------
    const int w = slot - 16;
    const int bmb = b0 + (w >> 3);
    const int r0 = (w & 7)*64;
    const int rl = tid & 63, bl = (tid >> 6) & 1, half = tid >> 7;
    const int j = (rl >> 4)*256 + w*16 + (rl & 15);
    for (int t = 0; t <= 1000; ++t){
      // stage h_{t-1} for both batches of this group
      l_h[tid]       = afload(hbuf + b0*256 + tid);
      l_h[256 + tid] = afload(hbuf + b0*256 + 256 + tid);
      __syncthreads();
      if (t >= 1){
        const int r = r0 + (tid & 63), kq = tid >> 6;
        const float* wr = Wmel + r*256 + kq*64;       // fp32: direct mel path
        const float* hp = l_h + (w >> 3)*256 + kq*64;
        float mp = 0.f;
        #pragma unroll
        for (int k = 0; k < 64; k += 8)
          mp += dot8f(*(const float4*)(wr + k), *(const float4*)(wr + k + 4),
                      *(const float4*)(hp + k), *(const float4*)(hp + k + 4));
        l_t4[kq][tid & 63] = mp;
        __syncthreads();
        if (tid < 64){
          float v = l_t4[0][tid] + l_t4[1][tid] + l_t4[2][tid] + l_t4[3][tid] + bmel[r0 + tid];
          out_mel[((size_t)bmb*1000 + (t-1))*512 + r0 + tid] = v;
        }
        if ((w & 7) == 0 && tid < 64){
          const float* hp2 = l_h + (w >> 3)*256;
          float sp = 0.f;
          #pragma unroll
          for (int k2 = 0; k2 < 4; ++k2) sp += Wstop[tid*4 + k2] * hp2[tid*4 + k2];
          #pragma unroll
          for (int off = 32; off; off >>= 1) sp += __shfl_xor(sp, off);
          if (tid == 0) out_stop[bmb*1000 + (t-1)] = sp + bstop[0];
        }
      }
      if (t == 1000) break;
      {  // phase A: W2m @ h_{t-1} partials (bf16 weights)
        const u16* wr = W2m + j*256 + half*128;
        const float* hp = l_h + bl*256 + half*128;
        float acc = 0.f;
        #pragma unroll 4
        for (int k = 0; k < 128; k += 8)
          acc += dot8(*(const uint4*)(wr + k), *(const float4*)(hp + k), *(const float4*)(hp + k + 4));
        l_w2[tid] = acc;
      }
      bar_arrive(barA, slot, t+1);
      bar_wait(barA, 32, t+1);       // wait for attended partials
      // reduce partials over heads -> l_att[2][512]   (bo folded into bg0/bgp)
      for (int i = tid; i < 1024; i += 256){
        const int bl3 = i >> 9, jj = i & 511;
        const float* ap = attb + ((size_t)(b0 + bl3)*8)*512 + jj;
        float s2 = 0.f;
        #pragma unroll
        for (int h8 = 0; h8 < 8; ++h8) s2 += afload(ap + h8*512);
        l_att[i] = s2;
      }
      __syncthreads();
      {  // phase B: gates = W1@attended + W2m@h + bias -> h_t (bf16 W1)
        const u16* wr = W1b + j*512 + half*256;
        const float* ap2 = l_att + bl*512 + half*256;
        float acc = 0.f;
        #pragma unroll 4
        for (int k = 0; k < 256; k += 8)
          acc += dot8(*(const uint4*)(wr + k), *(const float4*)(ap2 + k), *(const float4*)(ap2 + k + 4));
        l_gc[tid] = acc;
      }
      __syncthreads();
      if (tid < 128){
        const int rl2 = tid & 63, bl2 = tid >> 6;
        const int j2 = (rl2 >> 4)*256 + w*16 + (rl2 & 15);
        float gate = l_gc[bl2*64 + rl2] + l_gc[128 + bl2*64 + rl2]
                   + l_w2[bl2*64 + rl2] + l_w2[128 + bl2*64 + rl2]
                   + ((t == 0) ? bg0[j2] : bgp[j2]);
        l_gate[bl2*64 + rl2] = gate;
      }
      __syncthreads();
      if (tid < 32){
        const int il = tid & 15, bl2 = tid >> 4;
        float ig = l_gate[bl2*64 + il];
        float gg = l_gate[bl2*64 + 32 + il];
        float og = l_gate[bl2*64 + 48 + il];
        float c = sigm(ig)*tanhf(gg);              // decoder c_prev == 0 every step
        afstore(hbuf + (b0 + bl2)*256 + w*16 + il, sigm(og)*tanhf(c));
      }
      bar_arrive(barB, w, t+1);
      bar_wait(barB, 16, t+1);
    }
  }
}

extern "C" void kernel_launch(void* const* d_in, const int* in_sizes, int n_in,
                              void* d_out, int out_size, void* d_ws, size_t ws_size,
                              hipStream_t stream){
  const int*   tok = (const int*)d_in[0];
  const int*   spk = (const int*)d_in[1];
  const float* emb_text = (const float*)d_in[2];
  const float* emb_spk  = (const float*)d_in[3];
  const float* WihF = (const float*)d_in[4];
  const float* WhhF = (const float*)d_in[5];
  const float* bihF = (const float*)d_in[6];
  const float* bhhF = (const float*)d_in[7];
  const float* WihB = (const float*)d_in[8];
  const float* WhhB = (const float*)d_in[9];
  const float* bihB = (const float*)d_in[10];
  const float* bhhB = (const float*)d_in[11];
  const float* Wq = (const float*)d_in[12];
  const float* bq = (const float*)d_in[13];
  const float* Wk = (const float*)d_in[14];
  const float* bk = (const float*)d_in[15];
  const float* Wv = (const float*)d_in[16];
  const float* bv = (const float*)d_in[17];
  const float* Wo = (const float*)d_in[18];
  const float* bo = (const float*)d_in[19];
  const float* decW = (const float*)d_in[20];
  /* d_in[21] dec_Whh dead (state re-zeroed every step) */
  const float* bih = (const float*)d_in[22];
  const float* bhh = (const float*)d_in[23];
  const float* Wmel = (const float*)d_in[24];
  const float* bmel = (const float*)d_in[25];
  const float* Wstop = (const float*)d_in[26];
  const float* bstop = (const float*)d_in[27];

  char* ws = (char*)d_ws;
  int*   bars   = (int*)(ws + WS_BAR);
  float* hbuf   = (float*)(ws + WS_HBUF);
  float* probs  = (float*)(ws + WS_PROBS);
  float* biasws = (float*)(ws + WS_BIAS);
  float* attb   = (float*)(ws + WS_ATTB);
  u16*   W2m    = (u16*)(ws + WS_W2M);
  float* Wqh    = (float*)(ws + WS_WQH);
  u16*   Wob    = (u16*)(ws + WS_WOB);
  u16*   W1b    = (u16*)(ws + WS_W1B);

  float* outf = (float*)d_out;
  float* encA = outf + OF_ENC_A;
  float* encB = outf + OF_ENC_B;
  float* xwf  = outf + OF_XWF;
  float* xwb  = outf + OF_XWB;

  k_init <<<32,   256, 0, stream>>>(bars, hbuf);
  k_xw   <<<2048, 256, 0, stream>>>(tok, spk, emb_text, emb_spk,
                                    WihF, bihF, bhhF, WihB, bihB, bhhB, xwf, xwb);
  k_enc  <<<256,  128, 0, stream>>>(xwf, xwb, WhhF, WhhB, encA, encB, bars);
  k_cvt  <<<3072, 256, 0, stream>>>(Wo, decW, Wob, W1b);
  k_fuse <<<384,  256, 0, stream>>>(decW, Wmel, Wq, W2m, Wqh);
  k_bias <<<6,    256, 0, stream>>>(Wq, bq, bmel, decW, bo, bih, bhh, biasws);
  k_proj <<<1024, 256, 0, stream>>>(encA, encB, Wk, bk, Wv, bv, outf);
  k_decode<<<256, 256, 0, stream>>>(Wmel, bmel, Wstop, bstop, bq,
                                    Wob, W1b, W2m, Wqh, biasws,
                                    hbuf, attb, probs, bars, outf);
}

// Round 10
// 12078.403 us; speedup vs baseline: 3.0285x; 1.3039x over previous
//
#include <hip/hip_runtime.h>
#include <hip/hip_bf16.h>

// TTS: embed -> BiLSTM encoder -> K/V proj -> 1000-step autoregressive decode.
// Decode weights: Wcg=W1@Wo bf16 (single rounding of fp32 product), W2m bf16,
// Wmel/Wqh/K/V fp32; working set 2.5MB/XCD = L2-resident. fp32 accumulate.
// Sync: fence-free flag barriers; cross-block data via agent-scope RELAXED
// atomics (coherence-point, no L2 invalidate) staged into LDS. Attention
// publishes 64-float ctx/head (not 512 Wo-partials); gates do Wcg@ctx.
// barA = 16 attention arrivals only; barB = 16 gate arrivals.

typedef unsigned short u16;
typedef unsigned int   u32;
#define DI __device__ __forceinline__

// ---- ws layout (bytes), total 2368KB ----
static constexpr size_t WS_BAR   = 0;              // int[49152] 192KB (flag lines)
static constexpr size_t WS_HBUF  = 192*1024;       // fp32 [16][256] 16KB
static constexpr size_t WS_PROBS = 208*1024;       // fp32 [16][8][128] 64KB
static constexpr size_t WS_BIAS  = 272*1024;       // fp32 bqp[512]|bg0[1024]|bgp[1024]
static constexpr size_t WS_CTX   = 288*1024;       // fp32 [16][512] 32KB
static constexpr size_t WS_W2M   = 320*1024;       // bf16 [1024][256] 512KB
static constexpr size_t WS_WQH   = 832*1024;       // fp32 [512][256]  512KB
static constexpr size_t WS_WCG   = 1344*1024;      // bf16 [1024][512] 1MB -> 2368KB

// ---- d_out scratch (float indices; d_out = 8,210,048 floats) ----
static constexpr size_t OF_ENC_A = 262144;         // fp32 [8][128][512] b=0..7
static constexpr size_t OF_ENC_B = 1286144;        // fp32 [8][128][512] b=8..15
static constexpr size_t OF_XWF   = 4015744;        // fp32 [2048][1024]
static constexpr size_t OF_XWB   = 6112896;        // fp32 [2048][1024] -> 8210048
// K/V slot (group g, batch sub s): outf + g*1024000 + s*131072 (K then V^T)

DI float bf2f(u16 u){ union{u32 i; float f;} v; v.i = ((u32)u)<<16; return v.f; }
DI u16 f2bf(float f){ union{float f; u32 i;} v; v.f = f;
  u32 r = v.i + 0x7fffu + ((v.i>>16)&1u); return (u16)(r>>16); }
DI float2 bf2x(u32 u){ union{u32 i; float f;} a,b; a.i = u<<16; b.i = u & 0xffff0000u;
  float2 r; r.x = a.f; r.y = b.f; return r; }
DI float dot8(uint4 wv, float4 a, float4 b){   // bf16 weights x fp32 acts
  float2 w0 = bf2x(wv.x), w1 = bf2x(wv.y), w2 = bf2x(wv.z), w3 = bf2x(wv.w);
  return w0.x*a.x + w0.y*a.y + w1.x*a.z + w1.y*a.w
       + w2.x*b.x + w2.y*b.y + w3.x*b.z + w3.y*b.w;
}
DI float dot8f(float4 wa, float4 wb, float4 a, float4 b){
  return wa.x*a.x + wa.y*a.y + wa.z*a.z + wa.w*a.w
       + wb.x*b.x + wb.y*b.y + wb.z*b.z + wb.w*b.w;
}
DI float sigm(float x){ return 1.f/(1.f + __expf(-x)); }

// agent-scope relaxed atomics: coherence-point access, no fence needed.
DI float afload(const float* p){
  return __hip_atomic_load(p, __ATOMIC_RELAXED, __HIP_MEMORY_SCOPE_AGENT);
}
DI void afstore(float* p, float v){
  __hip_atomic_store(p, v, __ATOMIC_RELAXED, __HIP_MEMORY_SCOPE_AGENT);
}

// ---- fence-free flag barrier ----
DI void bar_arrive(int* flags, int myidx, int t){
  __syncthreads();
  if (threadIdx.x == 0){
    __builtin_amdgcn_s_waitcnt(0);
    __hip_atomic_store(flags + myidx*32, t, __ATOMIC_RELAXED, __HIP_MEMORY_SCOPE_AGENT);
  }
}
DI void bar_wait(int* flags, int n, int t){
  if (threadIdx.x < 64){
    const int idx = threadIdx.x & (n-1);
    int v = __hip_atomic_load(flags + idx*32, __ATOMIC_RELAXED, __HIP_MEMORY_SCOPE_AGENT);
    while (__any(v < t)){
      __builtin_amdgcn_s_sleep(1);
      if (v < t)
        v = __hip_atomic_load(flags + idx*32, __ATOMIC_RELAXED, __HIP_MEMORY_SCOPE_AGENT);
    }
  }
  __asm__ __volatile__("" ::: "memory");
  __syncthreads();
}

__global__ __launch_bounds__(256) void k_init(int* bars, float* hbuf){
  const int i = blockIdx.x*256 + threadIdx.x;   // 32 blocks
  for (int k = i; k < 49152; k += 32*256) bars[k] = 0;
  if (i < 4096) hbuf[i] = 0.f;
}

// fused embed + x@Wih.T + biases -> xw fp32. 2048 blocks.
__global__ __launch_bounds__(256) void k_xw(
    const int* __restrict__ tok, const int* __restrict__ spk,
    const float* __restrict__ et, const float* __restrict__ es,
    const float* __restrict__ WihF, const float* __restrict__ bihF, const float* __restrict__ bhhF,
    const float* __restrict__ WihB, const float* __restrict__ bihB, const float* __restrict__ bhhB,
    float* __restrict__ xwf, float* __restrict__ xwb){
  const int tid = threadIdx.x, bi = blockIdx.x;
  const int dir = bi & 1, jc = (bi >> 1) & 3, btg = bi >> 3;
  const int j = jc*256 + tid;
  const float* W = (dir ? WihB : WihF) + j*256;
  const float bias = (dir ? bihB : bihF)[j] + (dir ? bhhB : bhhF)[j];
  float* xw = dir ? xwb : xwf;

  __shared__ __align__(16) float lx[8][256];
  #pragma unroll
  for (int r = 0; r < 8; ++r){
    const int bt = btg*8 + r;
    lx[r][tid] = et[tok[bt]*256 + tid] + es[spk[bt>>7]*256 + tid];
  }
  __syncthreads();

  float acc[8];
  #pragma unroll
  for (int k2 = 0; k2 < 8; ++k2) acc[k2] = bias;
  for (int h = 0; h < 256; h += 8){
    float4 w0 = *(const float4*)(W + h);
    float4 w1 = *(const float4*)(W + h + 4);
    #pragma unroll
    for (int k2 = 0; k2 < 8; ++k2)
      acc[k2] += dot8f(w0, w1, *(const float4*)(&lx[k2][h]), *(const float4*)(&lx[k2][h+4]));
  }
  #pragma unroll
  for (int k2 = 0; k2 < 8; ++k2) xw[(btg*8 + k2)*1024 + j] = acc[k2];
}

// Wcg = W1@Wo -> bf16 [1024,512]; W2m = W2@Wmel -> bf16 [1024,256];
// Wqh = Wq@Wmel -> fp32 [512,256]. 896 blocks.
__global__ __launch_bounds__(256) void k_fuse(
    const float* __restrict__ decW, const float* __restrict__ Wo,
    const float* __restrict__ Wmel, const float* __restrict__ Wq,
    u16* __restrict__ Wcg, u16* __restrict__ W2m, float* __restrict__ Wqh){
  const int tid = threadIdx.x, blk = blockIdx.x;
  float acc[4] = {0.f,0.f,0.f,0.f};
  if (blk < 512){
    const int g0 = (blk >> 1)*4, e = (blk & 1)*256 + tid;
    for (int jj = 0; jj < 512; ++jj){
      float wo = Wo[jj*512 + e];
      #pragma unroll
      for (int i2 = 0; i2 < 4; ++i2) acc[i2] += decW[(g0+i2)*1024 + jj] * wo;
    }
    #pragma unroll
    for (int i2 = 0; i2 < 4; ++i2) Wcg[(g0+i2)*512 + e] = f2bf(acc[i2]);
  } else if (blk < 768){
    const int g0 = (blk - 512)*4, h = tid;
    for (int m = 0; m < 512; ++m){
      float wm = Wmel[m*256 + h];
      #pragma unroll
      for (int i2 = 0; i2 < 4; ++i2) acc[i2] += decW[(g0+i2)*1024 + 512 + m] * wm;
    }
    #pragma unroll
    for (int i2 = 0; i2 < 4; ++i2) W2m[(g0+i2)*256 + h] = f2bf(acc[i2]);
  } else {
    const int j0 = (blk - 768)*4, h = tid;
    for (int e = 0; e < 512; ++e){
      float wm = Wmel[e*256 + h];
      #pragma unroll
      for (int i2 = 0; i2 < 4; ++i2) acc[i2] += Wq[(j0+i2)*512 + e] * wm;
    }
    #pragma unroll
    for (int i2 = 0; i2 < 4; ++i2) Wqh[(j0+i2)*256 + h] = acc[i2];
  }
}

__global__ __launch_bounds__(256) void k_bias(
    const float* __restrict__ Wq, const float* __restrict__ bq, const float* __restrict__ bmel,
    const float* __restrict__ decW, const float* __restrict__ bo,
    const float* __restrict__ bih, const float* __restrict__ bhh, float* __restrict__ biasws){
  const int o = blockIdx.x*256 + threadIdx.x;   // 6 blocks -> 1536
  if (o < 512){
    float s = bq[o];
    for (int e = 0; e < 512; ++e) s += Wq[o*512 + e] * bmel[e];
    biasws[o] = s;                               // bq' = Wq@bmel + bq
  } else {
    const int gr = o - 512;
    float s1 = bih[gr] + bhh[gr];
    for (int jj = 0; jj < 512; ++jj) s1 += decW[gr*1024 + jj] * bo[jj];
    biasws[512 + gr] = s1;                       // bg0 = W1@bo + bih + bhh
    float s2 = s1;
    for (int m = 0; m < 512; ++m) s2 += decW[gr*1024 + 512 + m] * bmel[m];
    biasws[1536 + gr] = s2;                      // bg' = bg0 + W2@bmel
  }
}

// persistent BiLSTM encoder: 32 groups (dir,b) x 8 WGs x 128 thr. fp32.
__global__ __launch_bounds__(128) void k_enc(
    const float* __restrict__ xwf, const float* __restrict__ xwb,
    const float* __restrict__ WhhF, const float* __restrict__ WhhB,
    float* encA, float* encB, int* bars){
  const int tid = threadIdx.x;
  const int xcd = blockIdx.x & 7, sl = blockIdx.x >> 3;
  const int grp = xcd*4 + (sl >> 3);
  const int w = sl & 7;
  const int dir = grp & 1, b = grp >> 1;
  int* bar = bars + (16 + grp)*1024;
  const float* Whh = dir ? WhhB : WhhF;
  const float* xw = dir ? xwb : xwf;
  float* encb = (b < 8 ? encA : encB) + (size_t)(b & 7)*65536;
  const int q = tid >> 5, ii = tid & 31;
  const int j = q*256 + w*32 + ii;
  const float* wr = Whh + j*256;

  __shared__ __align__(16) float l_h[256];
  __shared__ float l_g[4][32];
  __shared__ float l_c[32];
  if (tid < 32) l_c[tid] = 0.f;
  __syncthreads();

  for (int it = 0; it < 128; ++it){
    const int ts = dir ? (127 - it) : it;
    float acc = xw[(b*128 + ts)*1024 + j];
    if (it > 0){
      const int tp = dir ? (ts + 1) : (ts - 1);
      const float* hp = encb + tp*512 + dir*256;
      for (int i = tid; i < 256; i += 128) l_h[i] = afload(hp + i);
      __syncthreads();
      #pragma unroll 4
      for (int k = 0; k < 256; k += 8)
        acc += dot8f(*(const float4*)(wr + k), *(const float4*)(wr + k + 4),
                     *(const float4*)(&l_h[k]), *(const float4*)(&l_h[k + 4]));
    }
    l_g[q][ii] = acc;
    __syncthreads();
    if (tid < 32){
      float ig = l_g[0][tid], fg = l_g[1][tid], gg = l_g[2][tid], og = l_g[3][tid];
      float c = sigm(fg)*l_c[tid] + sigm(ig)*tanhf(gg);
      l_c[tid] = c;
      afstore(encb + ts*512 + dir*256 + w*32 + tid, sigm(og)*tanhf(c));
    }
    bar_arrive(bar, w, it+1);
    bar_wait(bar, 8, it+1);
  }
}

// K,V projections fp32 -> per-group slot in d_out. 1024 blocks.
__global__ __launch_bounds__(256) void k_proj(
    const float* __restrict__ encA, const float* __restrict__ encB,
    const float* __restrict__ Wk, const float* __restrict__ bk,
    const float* __restrict__ Wv, const float* __restrict__ bv,
    float* outf){
  const int tid = threadIdx.x, x = blockIdx.x;
  const int role = x & 1, dc = (x >> 1) & 1, btg = x >> 2;
  const int row = dc*256 + tid;
  const float* W = (role ? Wv : Wk) + row*512;
  const float bias = (role ? bv : bk)[row];
  const int b = (btg*8) >> 7;
  const float* eb = (b < 8 ? encA : encB) + (size_t)(b & 7)*65536;
  float acc[8];
  #pragma unroll
  for (int k2 = 0; k2 < 8; ++k2) acc[k2] = bias;
  for (int e = 0; e < 512; e += 8){
    float4 wa = *(const float4*)(W + e);
    float4 wb = *(const float4*)(W + e + 4);
    #pragma unroll
    for (int k2 = 0; k2 < 8; ++k2){
      const float* ep = eb + ((btg*8 + k2) & 127)*512 + e;
      acc[k2] += dot8f(wa, wb, *(const float4*)(ep), *(const float4*)(ep + 4));
    }
  }
  const int head = row >> 6, dd = row & 63;
  float* kv = outf + (size_t)(b >> 1)*1024000 + (size_t)(b & 1)*131072;
  #pragma unroll
  for (int k2 = 0; k2 < 8; ++k2){
    const int ts = (btg*8 + k2) & 127;
    if (role == 0) kv[head*8192 + ts*64 + dd] = acc[k2];
    else           kv[65536 + head*8192 + dd*128 + ts] = acc[k2];
  }
}

// persistent decoder: 8 groups (b-pair) x 32 WGs x 256 thr; 2 fence-free
// flag-barriers/step. Attention publishes ctx (64/head); gates do Wcg@ctx.
__global__ __launch_bounds__(256) void k_decode(
    const float* __restrict__ Wmel, const float* __restrict__ bmel,
    const float* __restrict__ Wstop, const float* __restrict__ bstop,
    const float* __restrict__ bq,
    const u16* __restrict__ Wcg, const u16* __restrict__ W2m,
    const float* __restrict__ Wqh, const float* __restrict__ biasws,
    float* hbuf, float* ctxb, float* probs,
    int* bars, float* out){   // out NOT restrict: K/V slots alias mel region
  const int tid = threadIdx.x;
  const int g = blockIdx.x & 7, slot = blockIdx.x >> 3;
  const int b0 = g*2;
  int* barA = bars + g*1024;
  int* barB = bars + (8+g)*1024;
  const float* bqp = biasws;
  const float* bg0 = biasws + 512;
  const float* bgp = biasws + 1536;
  float* out_mel  = out;
  float* out_stop = out + 8192000;
  float* out_attn = out + 8208000;

  // fp32 K stride 68, V stride 132: conflict-free b128 row reads.
  __shared__ __align__(16) float lK[128*68];
  __shared__ __align__(16) float lV[64*132];
  __shared__ __align__(16) float l_t4[4][64];
  __shared__ __align__(16) float l_q[64];
  __shared__ __align__(16) float l_p[128];
  __shared__ float l_r[4];
  __shared__ __align__(16) float l_ct[1024];
  __shared__ __align__(16) float l_h[512];
  __shared__ float l_w2[256];
  __shared__ float l_gc[256];
  __shared__ float l_gate[128];

  if (slot < 16){
    // ---------------- attention slot (b,head) ----------------
    const int b = b0 + (slot >> 3), head = slot & 7;
    const int d = tid & 63, kq = tid >> 6;
    {  // prelude: K,V -> LDS from this group's own slot (before any mel write)
      const float* kv = out + (size_t)g*1024000 + (size_t)(slot >> 3)*131072;
      const float* gK = kv + head*8192;
      const float* gV = kv + 65536 + head*8192;
      for (int i = tid; i < 2048; i += 256){
        const int r = i >> 4, c = i & 15;
        *(float4*)(lK + r*68 + c*4) = *(const float4*)(gK + r*64 + c*4);
      }
      for (int i = tid; i < 2048; i += 256){
        const int r = i >> 5, c = i & 31;
        *(float4*)(lV + r*132 + c*4) = *(const float4*)(gV + r*128 + c*4);
      }
      __syncthreads();
    }
    const float* wqr = Wqh + (head*64 + d)*256 + kq*64;
    for (int t = 0; t < 1000; ++t){
      float qp = 0.f;
      if (t > 0){
        l_h[tid] = afload(hbuf + b*256 + tid);   // stage h_{t-1}
        __syncthreads();
        const float* hpq = l_h + kq*64;
        #pragma unroll
        for (int k = 0; k < 64; k += 8)
          qp += dot8f(*(const float4*)(wqr + k), *(const float4*)(wqr + k + 4),
                      *(const float4*)(hpq + k), *(const float4*)(hpq + k + 4));
      }
      l_t4[kq][d] = qp;
      __syncthreads();
      if (tid < 64){
        float qq = l_t4[0][tid] + l_t4[1][tid] + l_t4[2][tid] + l_t4[3][tid];
        qq += (t == 0) ? bq[head*64 + tid] : bqp[head*64 + tid];
        l_q[tid] = qq;
      }
      __syncthreads();
      float s = 0.f;
      if (tid < 128){
        const float* kr = lK + tid*68;
        #pragma unroll
        for (int k = 0; k < 64; k += 8)
          s += dot8f(*(const float4*)(kr + k), *(const float4*)(kr + k + 4),
                     *(const float4*)(l_q + k), *(const float4*)(l_q + k + 4));
        s *= 0.125f;
        float m = s;
        #pragma unroll
        for (int off = 32; off; off >>= 1) m = fmaxf(m, __shfl_xor(m, off));
        if ((tid & 63) == 0) l_r[tid >> 6] = m;
      }
      __syncthreads();
      float p = 0.f;
      if (tid < 128){
        float M = fmaxf(l_r[0], l_r[1]);
        p = __expf(s - M);
        float ss = p;
        #pragma unroll
        for (int off = 32; off; off >>= 1) ss += __shfl_xor(ss, off);
        if ((tid & 63) == 0) l_r[2 + (tid >> 6)] = ss;
      }
      __syncthreads();
      if (tid < 128){
        p /= (l_r[2] + l_r[3]);
        l_p[tid] = p;
        if (t == 999) afstore(probs + (b*8 + head)*128 + tid, p);
      }
      __syncthreads();
      {
        const float* vr = lV + d*132 + kq*32;
        float cp = 0.f;
        #pragma unroll
        for (int k = 0; k < 32; k += 8)
          cp += dot8f(*(const float4*)(vr + k), *(const float4*)(vr + k + 4),
                      *(const float4*)(l_p + kq*32 + k), *(const float4*)(l_p + kq*32 + k + 4));
        l_t4[kq][d] = cp;
      }
      __syncthreads();
      if (tid < 64)
        afstore(ctxb + b*512 + head*64 + tid,
                l_t4[0][tid] + l_t4[1][tid] + l_t4[2][tid] + l_t4[3][tid]);
      bar_arrive(barA, slot, t+1);   // publish ctx; don't wait on A
      bar_wait(barB, 16, t+1);       // wait for h_t
    }
    if (tid < 16){
      const int tt = (slot & 7)*16 + tid;
      float ssum = 0.f;
      #pragma unroll
      for (int h8 = 0; h8 < 8; ++h8) ssum += afload(probs + (b*8 + h8)*128 + tt);
      out_attn[b*128 + tt] = ssum * 0.125f;
    }
  } else {
    // ---------------- gate slot ----------------
    const int w = slot - 16;
    const int bmb = b0 + (w >> 3);
    const int r0 = (w & 7)*64;
    const int rl = tid & 63, bl = (tid >> 6) & 1, half = tid >> 7;
    const int j = (rl >> 4)*256 + w*16 + (rl & 15);
    for (int t = 0; t <= 1000; ++t){
      // stage h_{t-1} for both batches of this group
      l_h[tid]       = afload(hbuf + b0*256 + tid);
      l_h[256 + tid] = afload(hbuf + b0*256 + 256 + tid);
      __syncthreads();
      if (t >= 1){
        const int r = r0 + (tid & 63), kq = tid >> 6;
        const float* wr = Wmel + r*256 + kq*64;       // fp32: direct mel path
        const float* hp = l_h + (w >> 3)*256 + kq*64;
        float mp = 0.f;
        #pragma unroll
        for (int k = 0; k < 64; k += 8)
          mp += dot8f(*(const float4*)(wr + k), *(const float4*)(wr + k + 4),
                      *(const float4*)(hp + k), *(const float4*)(hp + k + 4));
        l_t4[kq][tid & 63] = mp;
        __syncthreads();
        if (tid < 64){
          float v = l_t4[0][tid] + l_t4[1][tid] + l_t4[2][tid] + l_t4[3][tid] + bmel[r0 + tid];
          out_mel[((size_t)bmb*1000 + (t-1))*512 + r0 + tid] = v;
        }
        if ((w & 7) == 0 && tid < 64){
          const float* hp2 = l_h + (w >> 3)*256;
          float sp = 0.f;
          #pragma unroll
          for (int k2 = 0; k2 < 4; ++k2) sp += Wstop[tid*4 + k2] * hp2[tid*4 + k2];
          #pragma unroll
          for (int off = 32; off; off >>= 1) sp += __shfl_xor(sp, off);
          if (tid == 0) out_stop[bmb*1000 + (t-1)] = sp + bstop[0];
        }
      }
      if (t == 1000) break;
      {  // phase A: W2m @ h_{t-1} partials (bf16 weights)
        const u16* wr = W2m + j*256 + half*128;
        const float* hp = l_h + bl*256 + half*128;
        float acc = 0.f;
        #pragma unroll 4
        for (int k = 0; k < 128; k += 8)
          acc += dot8(*(const uint4*)(wr + k), *(const float4*)(hp + k), *(const float4*)(hp + k + 4));
        l_w2[tid] = acc;
      }
      bar_wait(barA, 16, t+1);       // wait for ctx (attention arrivals only)
      for (int i = tid; i < 1024; i += 256)
        l_ct[i] = afload(ctxb + b0*512 + i);
      __syncthreads();
      {  // phase B: gates = Wcg@ctx + W2m@h + bias -> h_t (bf16 Wcg)
        const u16* wr = Wcg + j*512 + half*256;
        const float* cp = l_ct + bl*512 + half*256;
        float acc = 0.f;
        #pragma unroll 4
        for (int k = 0; k < 256; k += 8)
          acc += dot8(*(const uint4*)(wr + k), *(const float4*)(cp + k), *(const float4*)(cp + k + 4));
        l_gc[tid] = acc;
      }
      __syncthreads();
      if (tid < 128){
        const int rl2 = tid & 63, bl2 = tid >> 6;
        const int j2 = (rl2 >> 4)*256 + w*16 + (rl2 & 15);
        float gate = l_gc[bl2*64 + rl2] + l_gc[128 + bl2*64 + rl2]
                   + l_w2[bl2*64 + rl2] + l_w2[128 + bl2*64 + rl2]
                   + ((t == 0) ? bg0[j2] : bgp[j2]);
        l_gate[bl2*64 + rl2] = gate;
      }
      __syncthreads();
      if (tid < 32){
        const int il = tid & 15, bl2 = tid >> 4;
        float ig = l_gate[bl2*64 + il];
        float gg = l_gate[bl2*64 + 32 + il];
        float og = l_gate[bl2*64 + 48 + il];
        float c = sigm(ig)*tanhf(gg);              // decoder c_prev == 0 every step
        afstore(hbuf + (b0 + bl2)*256 + w*16 + il, sigm(og)*tanhf(c));
      }
      bar_arrive(barB, w, t+1);
      bar_wait(barB, 16, t+1);
    }
  }
}

extern "C" void kernel_launch(void* const* d_in, const int* in_sizes, int n_in,
                              void* d_out, int out_size, void* d_ws, size_t ws_size,
                              hipStream_t stream){
  const int*   tok = (const int*)d_in[0];
  const int*   spk = (const int*)d_in[1];
  const float* emb_text = (const float*)d_in[2];
  const float* emb_spk  = (const float*)d_in[3];
  const float* WihF = (const float*)d_in[4];
  const float* WhhF = (const float*)d_in[5];
  const float* bihF = (const float*)d_in[6];
  const float* bhhF = (const float*)d_in[7];
  const float* WihB = (const float*)d_in[8];
  const float* WhhB = (const float*)d_in[9];
  const float* bihB = (const float*)d_in[10];
  const float* bhhB = (const float*)d_in[11];
  const float* Wq = (const float*)d_in[12];
  const float* bq = (const float*)d_in[13];
  const float* Wk = (const float*)d_in[14];
  const float* bk = (const float*)d_in[15];
  const float* Wv = (const float*)d_in[16];
  const float* bv = (const float*)d_in[17];
  const float* Wo = (const float*)d_in[18];
  const float* bo = (const float*)d_in[19];
  const float* decW = (const float*)d_in[20];
  /* d_in[21] dec_Whh dead (state re-zeroed every step) */
  const float* bih = (const float*)d_in[22];
  const float* bhh = (const float*)d_in[23];
  const float* Wmel = (const float*)d_in[24];
  const float* bmel = (const float*)d_in[25];
  const float* Wstop = (const float*)d_in[26];
  const float* bstop = (const float*)d_in[27];

  char* ws = (char*)d_ws;
  int*   bars   = (int*)(ws + WS_BAR);
  float* hbuf   = (float*)(ws + WS_HBUF);
  float* probs  = (float*)(ws + WS_PROBS);
  float* biasws = (float*)(ws + WS_BIAS);
  float* ctxb   = (float*)(ws + WS_CTX);
  u16*   W2m    = (u16*)(ws + WS_W2M);
  float* Wqh    = (float*)(ws + WS_WQH);
  u16*   Wcg    = (u16*)(ws + WS_WCG);

  float* outf = (float*)d_out;
  float* encA = outf + OF_ENC_A;
  float* encB = outf + OF_ENC_B;
  float* xwf  = outf + OF_XWF;
  float* xwb  = outf + OF_XWB;

  k_init <<<32,   256, 0, stream>>>(bars, hbuf);
  k_xw   <<<2048, 256, 0, stream>>>(tok, spk, emb_text, emb_spk,
                                    WihF, bihF, bhhF, WihB, bihB, bhhB, xwf, xwb);
  k_enc  <<<256,  128, 0, stream>>>(xwf, xwb, WhhF, WhhB, encA, encB, bars);
  k_fuse <<<896,  256, 0, stream>>>(decW, Wo, Wmel, Wq, Wcg, W2m, Wqh);
  k_bias <<<6,    256, 0, stream>>>(Wq, bq, bmel, decW, bo, bih, bhh, biasws);
  k_proj <<<1024, 256, 0, stream>>>(encA, encB, Wk, bk, Wv, bv, outf);
  k_decode<<<256, 256, 0, stream>>>(Wmel, bmel, Wstop, bstop, bq,
                                    Wcg, W2m, Wqh, biasws,
                                    hbuf, ctxb, probs, bars, outf);
}